// Round 4
// baseline (466.492 us; speedup 1.0000x reference)
//
#include <hip/hip_runtime.h>
#include <math.h>

typedef __bf16 bf16x8 __attribute__((ext_vector_type(8)));
typedef __bf16 bf16x4 __attribute__((ext_vector_type(4)));
typedef float f32x4 __attribute__((ext_vector_type(4)));
typedef float f32x2 __attribute__((ext_vector_type(2)));
typedef unsigned int u32x2 __attribute__((ext_vector_type(2)));
typedef unsigned int u32x4 __attribute__((ext_vector_type(4)));

#define LOG2E 1.4426950408889634f
#define BCAP 8192  // per-bucket region capacity in part[] (expected load ~4340, 60-sigma margin)

static __device__ __forceinline__ float lrelu(float e) { return e > 0.0f ? e : 0.2f * e; }
static __device__ __forceinline__ float fexp2(float x) { return __builtin_amdgcn_exp2f(x); }

static __device__ __forceinline__ void dec16(u32x4 u, float* f) {
#pragma unroll
  for (int i = 0; i < 4; i++) {
    f32x2 a = __builtin_amdgcn_cvt_pk_f32_fp8(u[i], false);
    f32x2 b = __builtin_amdgcn_cvt_pk_f32_fp8(u[i], true);
    f[i * 4 + 0] = a.x;
    f[i * 4 + 1] = a.y;
    f[i * 4 + 2] = b.x;
    f[i * 4 + 3] = b.y;
  }
}

static __device__ __forceinline__ void dec8(unsigned int lo, unsigned int hi, float* f) {
  f32x2 a = __builtin_amdgcn_cvt_pk_f32_fp8(lo, false);
  f32x2 b = __builtin_amdgcn_cvt_pk_f32_fp8(lo, true);
  f32x2 c = __builtin_amdgcn_cvt_pk_f32_fp8(hi, false);
  f32x2 d = __builtin_amdgcn_cvt_pk_f32_fp8(hi, true);
  f[0] = a.x; f[1] = a.y; f[2] = b.x; f[3] = b.y;
  f[4] = c.x; f[5] = c.y; f[6] = d.x; f[7] = d.y;
}

// permuted-position -> true-channel map: p = blk*64 + l16*4 + ng  <->  c = blk*64 + ng*16 + l16
static __device__ __forceinline__ int cmap(int p) {
  return (p & ~63) + (p & 3) * 16 + ((p & 63) >> 2);
}

// ---------------- prep: weight transposes, zero bucket counters (x conversion removed) -------
__global__ void prep_kernel(const float* __restrict__ W0, __bf16* __restrict__ Bt0,
                            const float* __restrict__ W1, __bf16* __restrict__ Bt1,
                            const float* __restrict__ W2, __bf16* __restrict__ Bt2, int FIN,
                            int* __restrict__ cnt, int n) {
  int b = blockIdx.x;
  if (b < 256) {  // Bt0[256][FIN] = W0^T (x unpermuted)
    for (int k = threadIdx.x; k < FIN; k += 256) Bt0[b * FIN + k] = (__bf16)W0[k * 256 + b];
    return;
  }
  b -= 256;
  if (b < 256) {  // Bt1[n][p] = W1[cmap(p)][n]
    int k = threadIdx.x;
    Bt1[b * 256 + k] = (__bf16)W1[cmap(k) * 256 + b];
    return;
  }
  b -= 256;
  if (b < 64) {  // Bt2[n][p] = W2[cmap(p)][n]
    int k = threadIdx.x;
    Bt2[b * 256 + k] = (__bf16)W2[cmap(k) * 64 + b];
    return;
  }
  b -= 64;
  // zero bucket counters (re-init every launch: harness re-poisons d_ws)
  int i = b * 256 + threadIdx.x;
  if (i < n) cnt[i] = 0;
}

// ------- FUSED: layer-0 GEMM (f32 A read, in-register bf16 cvt) + bucket-partition --------
template <int K, int NT>
__global__ __launch_bounds__(256) void gemm_part_kernel(
    const float* __restrict__ A, const __bf16* __restrict__ Bt,
    const float* __restrict__ a_src, const float* __restrict__ a_dst,
    unsigned char* __restrict__ C, float* __restrict__ es, float* __restrict__ ed, int M,
    int gmx, const int* __restrict__ srcE, const int* __restrict__ dstE,
    int* __restrict__ bucket_cnt, unsigned int* __restrict__ part, int E, int EE, int n) {
  constexpr int Nc = NT * 64;
  constexpr int H = NT;
  constexpr int KS = K / 32;
  __shared__ __bf16 Bs[2][NT * 64][40];
  if ((int)blockIdx.x >= gmx) {
    int tid = threadIdx.x;
    int* hist = (int*)&Bs[0][0][0];  // 256 ints
    int* gbase = hist + 256;         // 256 ints (2KB total, fits in Bs)
    hist[tid] = 0;
    __syncthreads();
    int ab = ((int)blockIdx.x - gmx) * 4096;
    int sv[16], dv[16];
#pragma unroll
    for (int t = 0; t < 16; t++) {
      int e = ab + t * 256 + tid;
      if (e < EE) {
        if (e < E) { sv[t] = srcE[e]; dv[t] = dstE[e]; }
        else { sv[t] = dv[t] = e - E; }  // self-loops
      } else { sv[t] = -1; dv[t] = 0; }
    }
    int lr[16];
#pragma unroll
    for (int t = 0; t < 16; t++)
      if (sv[t] >= 0) lr[t] = atomicAdd(&hist[dv[t] >> 8], 1);
    __syncthreads();
    int NB = (n + 255) >> 8;
    // one global reserve per bucket; counters padded to 64B lines to avoid line ping-pong
    gbase[tid] = (tid < NB && hist[tid] > 0) ? atomicAdd(&bucket_cnt[tid * 16], hist[tid]) : 0;
    __syncthreads();
#pragma unroll
    for (int t = 0; t < 16; t++)
      if (sv[t] >= 0) {
        int bk = dv[t] >> 8;
        part[(size_t)bk * BCAP + gbase[bk] + lr[t]] =
            (unsigned int)sv[t] | ((unsigned int)(dv[t] & 255) << 24);  // N < 2^24
      }
    return;
  }
  int bid = blockIdx.x;
  int tid = threadIdx.x;
  int wave = tid >> 6;
  int lane = tid & 63;
  int quad = lane >> 4;
  int l16 = lane & 15;
  int rowBase = bid * 64 + wave * 16;
  f32x4 acc[NT * 4] = {};
  int arow = rowBase + l16;
  arow = (arow < M) ? arow : (M - 1);
  const float* Aptr = &A[(size_t)arow * K + quad * 8];
  int sr = tid >> 2;
  int sc = (tid & 3) * 8;
  // prefetch the whole per-lane A slice, converting f32 -> bf16 in-register (xb pass removed)
  bf16x8 af[KS];
#pragma unroll
  for (int s = 0; s < KS; s++) {
    f32x4 lo = *(const f32x4*)&Aptr[s * 32];
    f32x4 hi = *(const f32x4*)&Aptr[s * 32 + 4];
    bf16x8 t;
    t[0] = (__bf16)lo.x; t[1] = (__bf16)lo.y; t[2] = (__bf16)lo.z; t[3] = (__bf16)lo.w;
    t[4] = (__bf16)hi.x; t[5] = (__bf16)hi.y; t[6] = (__bf16)hi.z; t[7] = (__bf16)hi.w;
    af[s] = t;
  }
  // stage buffer 0
#pragma unroll
  for (int it = 0; it < NT; it++) {
    int r = it * 64 + sr;
    *(bf16x8*)&Bs[0][r][sc] = *(const bf16x8*)&Bt[(size_t)r * K + sc];
  }
  __syncthreads();
#pragma unroll
  for (int s = 0; s < KS; s++) {
    int cur = s & 1;
    if (s + 1 < KS) {  // stage next K-slice into the other buffer (overlaps MFMA below)
#pragma unroll
      for (int it = 0; it < NT; it++) {
        int r = it * 64 + sr;
        *(bf16x8*)&Bs[cur ^ 1][r][sc] = *(const bf16x8*)&Bt[(size_t)r * K + (s + 1) * 32 + sc];
      }
    }
#pragma unroll
    for (int ng = 0; ng < NT * 4; ng++) {
      bf16x8 b = *(const bf16x8*)&Bs[cur][ng * 16 + l16][quad * 8];
      acc[ng] = __builtin_amdgcn_mfma_f32_16x16x32_bf16(af[s], b, acc[ng], 0, 0, 0);
    }
    __syncthreads();
  }
  float asv[NT * 4], adv[NT * 4];
#pragma unroll
  for (int ng = 0; ng < NT * 4; ng++) {
    int c = (ng >> 2) * 64 + (ng & 3) * 16 + l16;
    asv[ng] = a_src[c];
    adv[ng] = a_dst[c];
  }
#pragma unroll
  for (int r = 0; r < 4; r++) {
    int row = rowBase + quad * 4 + r;
#pragma unroll
    for (int h = 0; h < H; h++) {
      float ss = 0.f, sd = 0.f;
#pragma unroll
      for (int g = 0; g < 4; g++) {
        float hv = acc[h * 4 + g][r];
        ss += hv * asv[h * 4 + g];
        sd += hv * adv[h * 4 + g];
      }
#pragma unroll
      for (int o = 1; o < 16; o <<= 1) {
        ss += __shfl_xor(ss, o);
        sd += __shfl_xor(sd, o);
      }
      if (row < M) {
        if (l16 == 0) {
          es[row * H + h] = ss * LOG2E;  // pre-scaled for exp2 in aggregate
          ed[row * H + h] = sd * LOG2E;
        }
        unsigned int pk = 0;
        pk = __builtin_amdgcn_cvt_pk_fp8_f32(acc[h * 4 + 0][r], acc[h * 4 + 1][r], pk, false);
        pk = __builtin_amdgcn_cvt_pk_fp8_f32(acc[h * 4 + 2][r], acc[h * 4 + 3][r], pk, true);
        *(unsigned int*)&C[(size_t)row * Nc + h * 64 + l16 * 4] = pk;
      }
    }
  }
}

// ------- per-bucket CSR finalize: one block per 256-node bucket, all ranks in LDS --------
__global__ __launch_bounds__(1024) void bucket_csr_kernel(
    const unsigned int* __restrict__ part, const int* __restrict__ bucket_cnt,
    int* __restrict__ offsets, int* __restrict__ src_sorted, int n, int EE) {
  __shared__ int sc[256];
  __shared__ int excl[256];
  __shared__ int run[256];
  int tid = threadIdx.x;
  int b = blockIdx.x;
  int NB = (n + 255) >> 8;
  if (tid < 256) sc[tid] = (tid < NB) ? bucket_cnt[tid * 16] : 0;
  __syncthreads();
  for (int d = 1; d < 256; d <<= 1) {
    int t = 0;
    if (tid < 256 && tid >= d) t = sc[tid - d];
    __syncthreads();
    if (tid < 256) sc[tid] += t;
    __syncthreads();
  }
  int base = (b == 0) ? 0 : sc[b - 1];
  int cb = sc[b] - base;
  const unsigned int* mypart = part + (size_t)b * BCAP;
  if (tid < 256) run[tid] = 0;
  __syncthreads();
  for (int i = tid; i < cb; i += 1024) atomicAdd(&run[mypart[i] >> 24], 1);
  __syncthreads();
  int myc = (tid < 256) ? run[tid] : 0;
  if (tid < 256) sc[tid] = myc;
  __syncthreads();
  for (int d = 1; d < 256; d <<= 1) {
    int t = 0;
    if (tid < 256 && tid >= d) t = sc[tid - d];
    __syncthreads();
    if (tid < 256) sc[tid] += t;
    __syncthreads();
  }
  if (tid < 256) {
    excl[tid] = sc[tid] - myc;
    int node = b * 256 + tid;
    if (node < n) offsets[node] = base + excl[tid];
    run[tid] = 0;
  }
  if (b == 0 && tid == 0) offsets[n] = EE;
  __syncthreads();
  for (int i = tid; i < cb; i += 1024) {
    unsigned int p = mypart[i];
    int j = p >> 24;
    int r = atomicAdd(&run[j], 1);
    src_sorted[base + excl[j] + r] = (int)(p & 0xFFFFFFu);
  }
}

// ------- FUSED aggregate(64 nodes -> LDS A-tile) + GEMM(A-tile @ Bt -> next layer) ----------
// Phase 1: wave w aggregates nodes [bid*64 + w*16, +16) from hin (fp8 gather, quads=4 edges),
// applies softmax-normalize + bias + relu, writes bf16 rows into LDS Atile.
// Phase 2: standard 64-row MFMA GEMM with A fragments read from Atile (kills the hB round-trip).
template <int NT>
__global__ __launch_bounds__(256) void agg_gemm_kernel(
    const unsigned char* __restrict__ hin, const int* __restrict__ offsets,
    const int* __restrict__ src_sorted, const float* __restrict__ esL,
    const float* __restrict__ edL, const float* __restrict__ biasL,
    const __bf16* __restrict__ Bt, const float* __restrict__ a_srcN,
    const float* __restrict__ a_dstN, unsigned char* __restrict__ C,
    float* __restrict__ esN, float* __restrict__ edN, int M) {
  constexpr int Nc = NT * 64;
  constexpr int H = NT;
  __shared__ __bf16 Atile[64][256];
  __shared__ __bf16 Bs[NT * 64][40];
  int tid = threadIdx.x;
  int wave = tid >> 6;
  int lane = tid & 63;
  int quad = lane >> 4;
  int l16 = lane & 15;
  int hd = l16 >> 2;
  // ---- phase 1: aggregation (always 4 heads x 64 ch input) ----
  for (int i = 0; i < 16; i++) {
    int lr = wave * 16 + i;
    int node = blockIdx.x * 64 + lr;
    float accv[16] = {};
    float sw = 0.f;
    float myEd = 0.f;
    int off = 0, deg = 0;
    if (node < M) {
      myEd = edL[node * 4 + hd];
      off = offsets[node];
      deg = offsets[node + 1] - off;
    }
    int j = 0;
    int s0a = 0, s1a = 0;
    if (j + 8 <= deg) {
      s0a = src_sorted[off + quad];
      s1a = src_sorted[off + 4 + quad];
    }
    for (; j + 8 <= deg;) {
      int jn = j + 8;
      int s0 = s0a, s1 = s1a;
      if (jn + 8 <= deg) {  // prefetch next iteration's indices
        s0a = src_sorted[off + jn + quad];
        s1a = src_sorted[off + jn + 4 + quad];
      }
      float e0 = esL[s0 * 4 + hd];
      float e1 = esL[s1 * 4 + hd];
      u32x4 u0 = *(const u32x4*)&hin[(size_t)s0 * 256 + l16 * 16];
      u32x4 u1 = *(const u32x4*)&hin[(size_t)s1 * 256 + l16 * 16];
      float w0 = fexp2(lrelu(e0 + myEd));
      float w1 = fexp2(lrelu(e1 + myEd));
      sw += w0 + w1;
      float f[16];
      dec16(u0, f);
#pragma unroll
      for (int k = 0; k < 16; k++) accv[k] += w0 * f[k];
      dec16(u1, f);
#pragma unroll
      for (int k = 0; k < 16; k++) accv[k] += w1 * f[k];
      j = jn;
    }
    for (; j < deg; j += 4) {  // tail: 1 edge per quad
      if (quad < deg - j) {
        int s = src_sorted[off + j + quad];
        float w = fexp2(lrelu(esL[s * 4 + hd] + myEd));
        sw += w;
        u32x4 u = *(const u32x4*)&hin[(size_t)s * 256 + l16 * 16];
        float f[16];
        dec16(u, f);
#pragma unroll
        for (int k = 0; k < 16; k++) accv[k] += w * f[k];
      }
    }
    sw += __shfl_xor(sw, 16);
    sw += __shfl_xor(sw, 32);
#pragma unroll
    for (int k = 0; k < 16; k++) {
      accv[k] += __shfl_xor(accv[k], 16);
      accv[k] += __shfl_xor(accv[k], 32);
    }
    if (quad == 0) {
      float invS = 1.0f / (sw + 1e-16f);
      bf16x8 o0, o1;
#pragma unroll
      for (int k = 0; k < 16; k++) {
        int c = hd * 64 + (k & 3) * 16 + (l16 & 3) * 4 + (k >> 2);  // cmap(l16*16+k)
        float v = (node < M) ? fmaxf(accv[k] * invS + biasL[c], 0.f) : 0.f;
        if (k < 8) o0[k] = (__bf16)v; else o1[k - 8] = (__bf16)v;
      }
      *(bf16x8*)&Atile[lr][l16 * 16] = o0;
      *(bf16x8*)&Atile[lr][l16 * 16 + 8] = o1;
    }
  }
  __syncthreads();
  // ---- phase 2: GEMM (K=256) ----
  int sr = tid >> 2;
  int sc = (tid & 3) * 8;
  int rowBase = blockIdx.x * 64 + wave * 16;
  int arow_l = wave * 16 + l16;
  bf16x8 af[8];
#pragma unroll
  for (int s = 0; s < 8; s++) af[s] = *(const bf16x8*)&Atile[arow_l][quad * 8 + s * 32];
  f32x4 acc[NT * 4] = {};
#pragma unroll
  for (int kb = 0; kb < 8; kb++) {
#pragma unroll
    for (int it = 0; it < NT; it++) {
      int r = it * 64 + sr;
      *(bf16x8*)&Bs[r][sc] = *(const bf16x8*)&Bt[(size_t)r * 256 + kb * 32 + sc];
    }
    __syncthreads();
#pragma unroll
    for (int ng = 0; ng < NT * 4; ng++) {
      bf16x8 b = *(const bf16x8*)&Bs[ng * 16 + l16][quad * 8];
      acc[ng] = __builtin_amdgcn_mfma_f32_16x16x32_bf16(af[kb], b, acc[ng], 0, 0, 0);
    }
    __syncthreads();
  }
  float asv[NT * 4], adv[NT * 4];
#pragma unroll
  for (int ng = 0; ng < NT * 4; ng++) {
    int c = (ng >> 2) * 64 + (ng & 3) * 16 + l16;
    asv[ng] = a_srcN[c];
    adv[ng] = a_dstN[c];
  }
#pragma unroll
  for (int r = 0; r < 4; r++) {
    int row = rowBase + quad * 4 + r;
#pragma unroll
    for (int h = 0; h < H; h++) {
      float ss = 0.f, sd = 0.f;
#pragma unroll
      for (int g = 0; g < 4; g++) {
        float hv = acc[h * 4 + g][r];
        ss += hv * asv[h * 4 + g];
        sd += hv * adv[h * 4 + g];
      }
#pragma unroll
      for (int o = 1; o < 16; o <<= 1) {
        ss += __shfl_xor(ss, o);
        sd += __shfl_xor(sd, o);
      }
      if (row < M) {
        if (l16 == 0) {
          esN[row * H + h] = ss * LOG2E;
          edN[row * H + h] = sd * LOG2E;
        }
        unsigned int pk = 0;
        pk = __builtin_amdgcn_cvt_pk_fp8_f32(acc[h * 4 + 0][r], acc[h * 4 + 1][r], pk, false);
        pk = __builtin_amdgcn_cvt_pk_fp8_f32(acc[h * 4 + 2][r], acc[h * 4 + 3][r], pk, true);
        *(unsigned int*)&C[(size_t)row * Nc + h * 64 + l16 * 4] = pk;
      }
    }
  }
}

// ------- aggregation, HC=64 + FUSED final linear: p[i] = (agg_i + b2) . lin_w (fp8 gather) ------
__global__ void agg64_kernel(const unsigned char* __restrict__ h, const int* __restrict__ offsets,
                             const int* __restrict__ src_sorted, const float* __restrict__ es,
                             const float* __restrict__ ed, const float* __restrict__ bias,
                             const float* __restrict__ lin_w, float* __restrict__ pnode, int n) {
  int node = blockIdx.x * (blockDim.x >> 6) + (threadIdx.x >> 6);
  int lane = threadIdx.x & 63;
  if (node >= n) return;
  int grp = lane >> 3;
  int l8 = lane & 7;
  float myEd = ed[node];
  int off = offsets[node];
  int deg = offsets[node + 1] - off;
  float acc[8] = {};
  float sw = 0.f;
  int j = 0;
  for (; j + 8 <= deg; j += 8) {
    int s = src_sorted[off + j + grp];
    float w = fexp2(lrelu(es[s] + myEd));
    sw += w;
    u32x2 u = *(const u32x2*)&h[(size_t)s * 64 + l8 * 8];
    float f[8];
    dec8(u.x, u.y, f);
#pragma unroll
    for (int k = 0; k < 8; k++) acc[k] += w * f[k];
  }
  if (j < deg && grp < deg - j) {
    int s = src_sorted[off + j + grp];
    float w = fexp2(lrelu(es[s] + myEd));
    sw += w;
    u32x2 u = *(const u32x2*)&h[(size_t)s * 64 + l8 * 8];
    float f[8];
    dec8(u.x, u.y, f);
#pragma unroll
    for (int k = 0; k < 8; k++) acc[k] += w * f[k];
  }
#pragma unroll
  for (int o = 8; o < 64; o <<= 1) {
    sw += __shfl_xor(sw, o);
#pragma unroll
    for (int k = 0; k < 8; k++) acc[k] += __shfl_xor(acc[k], o);
  }
  float invS = 1.0f / (sw + 1e-16f);
  float p = 0.f;
#pragma unroll
  for (int k = 0; k < 8; k++) {
    int c = (k & 3) * 16 + l8 * 2 + (k >> 2);  // cmap(l8*8+k)
    p += (acc[k] * invS + bias[c]) * lin_w[c];
  }
#pragma unroll
  for (int o = 1; o < 8; o <<= 1) p += __shfl_xor(p, o);
  if (lane == 0) pnode[node] = p;
}

// ---------------- FUSED pool+final: block g binary-searches its segment, reduces, writes out ----
static __device__ __forceinline__ int lowerb(const int* __restrict__ a, int n, int key) {
  int lo = 0, hi = n;
  while (lo < hi) {
    int mid = (lo + hi) >> 1;
    if (a[mid] < key) lo = mid + 1; else hi = mid;
  }
  return lo;
}

__global__ void poolfinal_kernel(const float* __restrict__ pnode, const int* __restrict__ batch,
                                 const float* __restrict__ lin_b, float* __restrict__ out, int n) {
  __shared__ float ws[4];
  int g = blockIdx.x;
  int start = lowerb(batch, n, g);
  int end = lowerb(batch, n, g + 1);
  float acc = 0.f;
  for (int i = start + threadIdx.x; i < end; i += 256) acc += pnode[i];
  for (int o = 32; o > 0; o >>= 1) acc += __shfl_down(acc, o);
  if ((threadIdx.x & 63) == 0) ws[threadIdx.x >> 6] = acc;
  __syncthreads();
  if (threadIdx.x == 0) {
    float total = ws[0] + ws[1] + ws[2] + ws[3];
    out[g] = total / fmaxf((float)(end - start), 1.0f) + lin_b[0];
  }
}

extern "C" void kernel_launch(void* const* d_in, const int* in_sizes, int n_in, void* d_out,
                              int out_size, void* d_ws, size_t ws_size, hipStream_t stream) {
  const float* x = (const float*)d_in[0];
  const int* edge_index = (const int*)d_in[1];
  const int* batch = (const int*)d_in[2];
  const float* W0 = (const float*)d_in[3];
  const float* a_src0 = (const float*)d_in[4];
  const float* a_dst0 = (const float*)d_in[5];
  const float* b0 = (const float*)d_in[6];
  const float* W1 = (const float*)d_in[7];
  const float* a_src1 = (const float*)d_in[8];
  const float* a_dst1 = (const float*)d_in[9];
  const float* b1 = (const float*)d_in[10];
  const float* W2 = (const float*)d_in[11];
  const float* a_src2 = (const float*)d_in[12];
  const float* a_dst2 = (const float*)d_in[13];
  const float* b2 = (const float*)d_in[14];
  const float* lin_w = (const float*)d_in[15];
  const float* lin_b = (const float*)d_in[16];
  float* out = (float*)d_out;

  const int N = in_sizes[2];      // 50000
  const int E = in_sizes[1] / 2;  // 800000
  const int EE = E + N;
  const int G = 64;
  const int FIN = in_sizes[0] / N;  // 128

  const int* srcArr = edge_index;
  const int* dstArr = edge_index + E;

  // workspace carve (256B aligned)
  size_t off = 0;
  auto alloc = [&](size_t bytes) -> void* {
    off = (off + 255) & ~(size_t)255;
    void* p = (char*)d_ws + off;
    off += bytes;
    return p;
  };
  unsigned char* hA = (unsigned char*)alloc((size_t)N * 256);  // layer-0 GEMM out, fp8 permuted
  unsigned char* hC = (unsigned char*)alloc((size_t)N * 256);  // fused1 out, fp8 permuted
  unsigned char* h2 = (unsigned char*)alloc((size_t)N * 64);   // fused2 out, fp8 permuted
  float* pnode = (float*)alloc((size_t)N * 4);
  __bf16* Bt0 = (__bf16*)alloc((size_t)256 * FIN * 2);
  __bf16* Bt1 = (__bf16*)alloc((size_t)256 * 256 * 2);
  __bf16* Bt2 = (__bf16*)alloc((size_t)64 * 256 * 2);
  float* es0 = (float*)alloc((size_t)N * 4 * 4);
  float* ed0 = (float*)alloc((size_t)N * 4 * 4);
  float* es1 = (float*)alloc((size_t)N * 4 * 4);
  float* ed1 = (float*)alloc((size_t)N * 4 * 4);
  float* es2 = (float*)alloc((size_t)N * 4);
  float* ed2 = (float*)alloc((size_t)N * 4);
  int* offsets = (int*)alloc((size_t)(N + 1) * 4);
  int* src_sorted = (int*)alloc((size_t)EE * 4);
  int* bucket_cnt = (int*)alloc((size_t)4096 * 4);  // 196 buckets padded to 64B stride
  (void)ws_size;

  int NB = (N + 255) >> 8;  // dst-range buckets (256 nodes each)

  // part[] lives only between gemm_part and bucket_csr; hC is first written by fused1
  // (after bucket_csr) -> alias part onto hC (NB*BCAP*4 = 6.4MB << 12.8MB).
  unsigned int* part = (unsigned int*)hC;

  int nwb = (N + 3) / 4;        // agg64: one node per wave, 4 waves/block
  int gmx = (N + 63) / 64;      // GEMM M-blocks (64 rows each)
  int nA = (EE + 4095) / 4096;  // partition blocks (4096 edges each)

  // ---- prep (weight transposes, zero bucket counters) ----
  prep_kernel<<<576 + 16, 256, 0, stream>>>(W0, Bt0, W1, Bt1, W2, Bt2, FIN, bucket_cnt, 4096);

  // ---- layer-0 GEMM (reads f32 x directly) + edge bucket-partition ----
  gemm_part_kernel<128, 4><<<gmx + nA, 256, 0, stream>>>(
      x, Bt0, a_src0, a_dst0, hA, es0, ed0, N, gmx, srcArr, dstArr, bucket_cnt, part, E, EE, N);

  // ---- per-bucket CSR finalize ----
  bucket_csr_kernel<<<NB, 1024, 0, stream>>>(part, bucket_cnt, offsets, src_sorted, N, EE);

  // ---- fused: layer-0 aggregate (hA) + layer-1 GEMM -> hC, es1/ed1 ----
  agg_gemm_kernel<4><<<gmx, 256, 0, stream>>>(hA, offsets, src_sorted, es0, ed0, b0, Bt1,
                                              a_src1, a_dst1, hC, es1, ed1, N);

  // ---- fused: layer-1 aggregate (hC) + layer-2 GEMM -> h2, es2/ed2 ----
  agg_gemm_kernel<1><<<gmx, 256, 0, stream>>>(hC, offsets, src_sorted, es1, ed1, b1, Bt2,
                                              a_src2, a_dst2, h2, es2, ed2, N);

  // ---- layer-2 aggregate + final linear fused ----
  agg64_kernel<<<nwb, 256, 0, stream>>>(h2, offsets, src_sorted, es2, ed2, b2, lin_w, pnode, N);

  // ---- fused global mean pool + bias (binary-search segments) ----
  poolfinal_kernel<<<G, 256, 0, stream>>>(pnode, batch, lin_b, out, N);
}

// Round 5
// 281.634 us; speedup vs baseline: 1.6564x; 1.6564x over previous
//
#include <hip/hip_runtime.h>
#include <math.h>

typedef __bf16 bf16x8 __attribute__((ext_vector_type(8)));
typedef __bf16 bf16x4 __attribute__((ext_vector_type(4)));
typedef float f32x4 __attribute__((ext_vector_type(4)));
typedef float f32x2 __attribute__((ext_vector_type(2)));
typedef unsigned int u32x2 __attribute__((ext_vector_type(2)));
typedef unsigned int u32x4 __attribute__((ext_vector_type(4)));

#define LOG2E 1.4426950408889634f
#define BCAP 8192  // per-bucket region capacity in part[] (expected load ~4340, 60-sigma margin)

static __device__ __forceinline__ float lrelu(float e) { return e > 0.0f ? e : 0.2f * e; }
static __device__ __forceinline__ float fexp2(float x) { return __builtin_amdgcn_exp2f(x); }

static __device__ __forceinline__ void dec16(u32x4 u, float* f) {
#pragma unroll
  for (int i = 0; i < 4; i++) {
    f32x2 a = __builtin_amdgcn_cvt_pk_f32_fp8(u[i], false);
    f32x2 b = __builtin_amdgcn_cvt_pk_f32_fp8(u[i], true);
    f[i * 4 + 0] = a.x;
    f[i * 4 + 1] = a.y;
    f[i * 4 + 2] = b.x;
    f[i * 4 + 3] = b.y;
  }
}

static __device__ __forceinline__ void dec8(unsigned int lo, unsigned int hi, float* f) {
  f32x2 a = __builtin_amdgcn_cvt_pk_f32_fp8(lo, false);
  f32x2 b = __builtin_amdgcn_cvt_pk_f32_fp8(lo, true);
  f32x2 c = __builtin_amdgcn_cvt_pk_f32_fp8(hi, false);
  f32x2 d = __builtin_amdgcn_cvt_pk_f32_fp8(hi, true);
  f[0] = a.x; f[1] = a.y; f[2] = b.x; f[3] = b.y;
  f[4] = c.x; f[5] = c.y; f[6] = d.x; f[7] = d.y;
}

// permuted-position -> true-channel map: p = blk*64 + l16*4 + ng  <->  c = blk*64 + ng*16 + l16
static __device__ __forceinline__ int cmap(int p) {
  return (p & ~63) + (p & 3) * 16 + ((p & 63) >> 2);
}

// ---------------- prep: weight transposes, zero bucket counters (x conversion folded into GEMM) -
__global__ void prep_kernel(const float* __restrict__ W0, __bf16* __restrict__ Bt0,
                            const float* __restrict__ W1, __bf16* __restrict__ Bt1,
                            const float* __restrict__ W2, __bf16* __restrict__ Bt2, int FIN,
                            int* __restrict__ cnt, int n) {
  int b = blockIdx.x;
  if (b < 256) {  // Bt0[256][FIN] = W0^T (x unpermuted)
    for (int k = threadIdx.x; k < FIN; k += 256) Bt0[b * FIN + k] = (__bf16)W0[k * 256 + b];
    return;
  }
  b -= 256;
  if (b < 256) {  // Bt1[n][p] = W1[cmap(p)][n]
    int k = threadIdx.x;
    Bt1[b * 256 + k] = (__bf16)W1[cmap(k) * 256 + b];
    return;
  }
  b -= 256;
  if (b < 64) {  // Bt2[n][p] = W2[cmap(p)][n]
    int k = threadIdx.x;
    Bt2[b * 256 + k] = (__bf16)W2[cmap(k) * 64 + b];
    return;
  }
  b -= 64;
  // zero bucket counters (re-init every launch: harness re-poisons d_ws)
  int i = b * 256 + threadIdx.x;
  if (i < n) cnt[i] = 0;
}

// ------- FUSED: layer-0 GEMM (f32 A read, in-register bf16 cvt) + bucket-partition --------
// Partition half: 196-bucket (dst>>8) LDS histogram, one global atomic per (block,bucket).
template <int K, int NT>
__global__ __launch_bounds__(256) void gemm_part_kernel(
    const float* __restrict__ A, const __bf16* __restrict__ Bt,
    const float* __restrict__ a_src, const float* __restrict__ a_dst,
    unsigned char* __restrict__ C, float* __restrict__ es, float* __restrict__ ed, int M,
    int gmx, const int* __restrict__ srcE, const int* __restrict__ dstE,
    int* __restrict__ bucket_cnt, unsigned int* __restrict__ part, int E, int EE, int n) {
  constexpr int Nc = NT * 64;
  constexpr int H = NT;
  constexpr int KS = K / 32;
  __shared__ __bf16 Bs[2][NT * 64][40];
  if ((int)blockIdx.x >= gmx) {
    int tid = threadIdx.x;
    int* hist = (int*)&Bs[0][0][0];  // 256 ints
    int* gbase = hist + 256;         // 256 ints (2KB total, fits in Bs)
    hist[tid] = 0;
    __syncthreads();
    int ab = ((int)blockIdx.x - gmx) * 4096;
    int sv[16], dv[16];
#pragma unroll
    for (int t = 0; t < 16; t++) {
      int e = ab + t * 256 + tid;
      if (e < EE) {
        if (e < E) { sv[t] = srcE[e]; dv[t] = dstE[e]; }
        else { sv[t] = dv[t] = e - E; }  // self-loops
      } else { sv[t] = -1; dv[t] = 0; }
    }
    int lr[16];
#pragma unroll
    for (int t = 0; t < 16; t++)
      if (sv[t] >= 0) lr[t] = atomicAdd(&hist[dv[t] >> 8], 1);
    __syncthreads();
    int NB = (n + 255) >> 8;
    // one global reserve per bucket; counters padded to 64B lines to avoid line ping-pong
    gbase[tid] = (tid < NB && hist[tid] > 0) ? atomicAdd(&bucket_cnt[tid * 16], hist[tid]) : 0;
    __syncthreads();
#pragma unroll
    for (int t = 0; t < 16; t++)
      if (sv[t] >= 0) {
        int bk = dv[t] >> 8;
        part[(size_t)bk * BCAP + gbase[bk] + lr[t]] =
            (unsigned int)sv[t] | ((unsigned int)(dv[t] & 255) << 24);  // N < 2^24
      }
    return;
  }
  int bid = blockIdx.x;
  int tid = threadIdx.x;
  int wave = tid >> 6;
  int lane = tid & 63;
  int quad = lane >> 4;
  int l16 = lane & 15;
  int rowBase = bid * 64 + wave * 16;
  f32x4 acc[NT * 4] = {};
  int arow = rowBase + l16;
  arow = (arow < M) ? arow : (M - 1);
  const float* Aptr = &A[(size_t)arow * K + quad * 8];
  int sr = tid >> 2;
  int sc = (tid & 3) * 8;
  // prefetch the whole per-lane A slice, converting f32 -> bf16 in-register (xb pass removed)
  bf16x8 af[KS];
#pragma unroll
  for (int s = 0; s < KS; s++) {
    f32x4 lo = *(const f32x4*)&Aptr[s * 32];
    f32x4 hi = *(const f32x4*)&Aptr[s * 32 + 4];
    bf16x8 t;
    t[0] = (__bf16)lo.x; t[1] = (__bf16)lo.y; t[2] = (__bf16)lo.z; t[3] = (__bf16)lo.w;
    t[4] = (__bf16)hi.x; t[5] = (__bf16)hi.y; t[6] = (__bf16)hi.z; t[7] = (__bf16)hi.w;
    af[s] = t;
  }
  // stage buffer 0
#pragma unroll
  for (int it = 0; it < NT; it++) {
    int r = it * 64 + sr;
    *(bf16x8*)&Bs[0][r][sc] = *(const bf16x8*)&Bt[(size_t)r * K + sc];
  }
  __syncthreads();
#pragma unroll
  for (int s = 0; s < KS; s++) {
    int cur = s & 1;
    if (s + 1 < KS) {  // stage next K-slice into the other buffer (overlaps MFMA below)
#pragma unroll
      for (int it = 0; it < NT; it++) {
        int r = it * 64 + sr;
        *(bf16x8*)&Bs[cur ^ 1][r][sc] = *(const bf16x8*)&Bt[(size_t)r * K + (s + 1) * 32 + sc];
      }
    }
#pragma unroll
    for (int ng = 0; ng < NT * 4; ng++) {
      bf16x8 b = *(const bf16x8*)&Bs[cur][ng * 16 + l16][quad * 8];
      acc[ng] = __builtin_amdgcn_mfma_f32_16x16x32_bf16(af[s], b, acc[ng], 0, 0, 0);
    }
    __syncthreads();
  }
  float asv[NT * 4], adv[NT * 4];
#pragma unroll
  for (int ng = 0; ng < NT * 4; ng++) {
    int c = (ng >> 2) * 64 + (ng & 3) * 16 + l16;
    asv[ng] = a_src[c];
    adv[ng] = a_dst[c];
  }
#pragma unroll
  for (int r = 0; r < 4; r++) {
    int row = rowBase + quad * 4 + r;
#pragma unroll
    for (int h = 0; h < H; h++) {
      float ss = 0.f, sd = 0.f;
#pragma unroll
      for (int g = 0; g < 4; g++) {
        float hv = acc[h * 4 + g][r];
        ss += hv * asv[h * 4 + g];
        sd += hv * adv[h * 4 + g];
      }
#pragma unroll
      for (int o = 1; o < 16; o <<= 1) {
        ss += __shfl_xor(ss, o);
        sd += __shfl_xor(sd, o);
      }
      if (row < M) {
        if (l16 == 0) {
          es[row * H + h] = ss * LOG2E;  // pre-scaled for exp2 in aggregate
          ed[row * H + h] = sd * LOG2E;
        }
        unsigned int pk = 0;
        pk = __builtin_amdgcn_cvt_pk_fp8_f32(acc[h * 4 + 0][r], acc[h * 4 + 1][r], pk, false);
        pk = __builtin_amdgcn_cvt_pk_fp8_f32(acc[h * 4 + 2][r], acc[h * 4 + 3][r], pk, true);
        *(unsigned int*)&C[(size_t)row * Nc + h * 64 + l16 * 4] = pk;
      }
    }
  }
}

// ------- per-bucket CSR finalize: one block per 256-node bucket, all ranks in LDS --------
__global__ __launch_bounds__(1024) void bucket_csr_kernel(
    const unsigned int* __restrict__ part, const int* __restrict__ bucket_cnt,
    int* __restrict__ offsets, int* __restrict__ src_sorted, int n, int EE) {
  __shared__ int sc[256];
  __shared__ int excl[256];
  __shared__ int run[256];
  int tid = threadIdx.x;
  int b = blockIdx.x;
  int NB = (n + 255) >> 8;
  if (tid < 256) sc[tid] = (tid < NB) ? bucket_cnt[tid * 16] : 0;
  __syncthreads();
  for (int d = 1; d < 256; d <<= 1) {
    int t = 0;
    if (tid < 256 && tid >= d) t = sc[tid - d];
    __syncthreads();
    if (tid < 256) sc[tid] += t;
    __syncthreads();
  }
  int base = (b == 0) ? 0 : sc[b - 1];
  int cb = sc[b] - base;
  const unsigned int* mypart = part + (size_t)b * BCAP;
  if (tid < 256) run[tid] = 0;
  __syncthreads();
  for (int i = tid; i < cb; i += 1024) atomicAdd(&run[mypart[i] >> 24], 1);
  __syncthreads();
  int myc = (tid < 256) ? run[tid] : 0;
  if (tid < 256) sc[tid] = myc;
  __syncthreads();
  for (int d = 1; d < 256; d <<= 1) {
    int t = 0;
    if (tid < 256 && tid >= d) t = sc[tid - d];
    __syncthreads();
    if (tid < 256) sc[tid] += t;
    __syncthreads();
  }
  if (tid < 256) {
    excl[tid] = sc[tid] - myc;
    int node = b * 256 + tid;
    if (node < n) offsets[node] = base + excl[tid];
    run[tid] = 0;
  }
  if (b == 0 && tid == 0) offsets[n] = EE;
  __syncthreads();
  for (int i = tid; i < cb; i += 1024) {
    unsigned int p = mypart[i];
    int j = p >> 24;
    int r = atomicAdd(&run[j], 1);
    src_sorted[base + excl[j] + r] = (int)(p & 0xFFFFFFu);
  }
}

// plain single-pass GEMM (layers 1/2): full-A prefetch + double-buffered Bs
template <int K, int NT>
__global__ __launch_bounds__(256) void gemm2_kernel(const __bf16* __restrict__ A,
                                                    const __bf16* __restrict__ Bt,
                                                    const float* __restrict__ a_src,
                                                    const float* __restrict__ a_dst,
                                                    unsigned char* __restrict__ C,
                                                    float* __restrict__ es,
                                                    float* __restrict__ ed, int M) {
  constexpr int Nc = NT * 64;
  constexpr int H = NT;
  constexpr int KS = K / 32;
  __shared__ __bf16 Bs[2][NT * 64][40];
  int tid = threadIdx.x;
  int wave = tid >> 6;
  int lane = tid & 63;
  int quad = lane >> 4;
  int l16 = lane & 15;
  int rowBase = blockIdx.x * 64 + wave * 16;
  f32x4 acc[NT * 4] = {};
  int arow = rowBase + l16;
  arow = (arow < M) ? arow : (M - 1);
  const __bf16* Aptr = &A[(size_t)arow * K + quad * 8];
  int sr = tid >> 2;
  int sc = (tid & 3) * 8;
  bf16x8 af[KS];
#pragma unroll
  for (int s = 0; s < KS; s++) af[s] = *(const bf16x8*)&Aptr[s * 32];
#pragma unroll
  for (int it = 0; it < NT; it++) {
    int r = it * 64 + sr;
    *(bf16x8*)&Bs[0][r][sc] = *(const bf16x8*)&Bt[(size_t)r * K + sc];
  }
  __syncthreads();
#pragma unroll
  for (int s = 0; s < KS; s++) {
    int cur = s & 1;
    if (s + 1 < KS) {
#pragma unroll
      for (int it = 0; it < NT; it++) {
        int r = it * 64 + sr;
        *(bf16x8*)&Bs[cur ^ 1][r][sc] = *(const bf16x8*)&Bt[(size_t)r * K + (s + 1) * 32 + sc];
      }
    }
#pragma unroll
    for (int ng = 0; ng < NT * 4; ng++) {
      bf16x8 b = *(const bf16x8*)&Bs[cur][ng * 16 + l16][quad * 8];
      acc[ng] = __builtin_amdgcn_mfma_f32_16x16x32_bf16(af[s], b, acc[ng], 0, 0, 0);
    }
    __syncthreads();
  }
  float asv[NT * 4], adv[NT * 4];
#pragma unroll
  for (int ng = 0; ng < NT * 4; ng++) {
    int c = (ng >> 2) * 64 + (ng & 3) * 16 + l16;
    asv[ng] = a_src[c];
    adv[ng] = a_dst[c];
  }
#pragma unroll
  for (int r = 0; r < 4; r++) {
    int row = rowBase + quad * 4 + r;
#pragma unroll
    for (int h = 0; h < H; h++) {
      float ss = 0.f, sd = 0.f;
#pragma unroll
      for (int g = 0; g < 4; g++) {
        float hv = acc[h * 4 + g][r];
        ss += hv * asv[h * 4 + g];
        sd += hv * adv[h * 4 + g];
      }
#pragma unroll
      for (int o = 1; o < 16; o <<= 1) {
        ss += __shfl_xor(ss, o);
        sd += __shfl_xor(sd, o);
      }
      if (row < M) {
        if (l16 == 0) {
          es[row * H + h] = ss * LOG2E;
          ed[row * H + h] = sd * LOG2E;
        }
        unsigned int pk = 0;
        pk = __builtin_amdgcn_cvt_pk_fp8_f32(acc[h * 4 + 0][r], acc[h * 4 + 1][r], pk, false);
        pk = __builtin_amdgcn_cvt_pk_fp8_f32(acc[h * 4 + 2][r], acc[h * 4 + 3][r], pk, true);
        *(unsigned int*)&C[(size_t)row * Nc + h * 64 + l16 * 4] = pk;
      }
    }
  }
}

// ------- aggregation, HC=256: fp8 gather, 4 edges/wave via quads, index-prefetch pipeline -------
__global__ void agg256_kernel(const unsigned char* __restrict__ h, const int* __restrict__ offsets,
                              const int* __restrict__ src_sorted, const float* __restrict__ es,
                              const float* __restrict__ ed, const float* __restrict__ bias,
                              __bf16* __restrict__ out, int n) {
  int node = blockIdx.x * (blockDim.x >> 6) + (threadIdx.x >> 6);
  int lane = threadIdx.x & 63;
  if (node >= n) return;
  int quad = lane >> 4;
  int l16 = lane & 15;  // positions l16*16 .. +16
  int hd = l16 >> 2;
  float myEd = ed[node * 4 + hd];
  int off = offsets[node];
  int deg = offsets[node + 1] - off;
  float acc[16] = {};
  float sw = 0.f;
  int j = 0;
  int s0a = 0, s1a = 0;
  if (j + 8 <= deg) {
    s0a = src_sorted[off + j + quad];
    s1a = src_sorted[off + j + 4 + quad];
  }
  for (; j + 8 <= deg;) {
    int jn = j + 8;
    int s0 = s0a, s1 = s1a;
    if (jn + 8 <= deg) {  // prefetch next iteration's indices
      s0a = src_sorted[off + jn + quad];
      s1a = src_sorted[off + jn + 4 + quad];
    }
    float e0 = es[s0 * 4 + hd];
    float e1 = es[s1 * 4 + hd];
    u32x4 u0 = *(const u32x4*)&h[(size_t)s0 * 256 + l16 * 16];
    u32x4 u1 = *(const u32x4*)&h[(size_t)s1 * 256 + l16 * 16];
    float w0 = fexp2(lrelu(e0 + myEd));
    float w1 = fexp2(lrelu(e1 + myEd));
    sw += w0 + w1;
    float f[16];
    dec16(u0, f);
#pragma unroll
    for (int k = 0; k < 16; k++) acc[k] += w0 * f[k];
    dec16(u1, f);
#pragma unroll
    for (int k = 0; k < 16; k++) acc[k] += w1 * f[k];
    j = jn;
  }
  for (; j < deg; j += 4) {  // tail: 1 edge per quad
    if (quad < deg - j) {
      int s = src_sorted[off + j + quad];
      float w = fexp2(lrelu(es[s * 4 + hd] + myEd));
      sw += w;
      u32x4 u = *(const u32x4*)&h[(size_t)s * 256 + l16 * 16];
      float f[16];
      dec16(u, f);
#pragma unroll
      for (int k = 0; k < 16; k++) acc[k] += w * f[k];
    }
  }
  sw += __shfl_xor(sw, 16);
  sw += __shfl_xor(sw, 32);
#pragma unroll
  for (int k = 0; k < 16; k++) {
    acc[k] += __shfl_xor(acc[k], 16);
    acc[k] += __shfl_xor(acc[k], 32);
  }
  float invS = 1.0f / (sw + 1e-16f);
  if (quad == 0) {
    bf16x8 o0, o1;
#pragma unroll
    for (int k = 0; k < 16; k++) {
      int c = hd * 64 + (k & 3) * 16 + (l16 & 3) * 4 + (k >> 2);  // cmap(l16*16+k)
      float v = fmaxf(acc[k] * invS + bias[c], 0.f);
      if (k < 8) o0[k] = (__bf16)v; else o1[k - 8] = (__bf16)v;
    }
    *(bf16x8*)&out[(size_t)node * 256 + l16 * 16] = o0;
    *(bf16x8*)&out[(size_t)node * 256 + l16 * 16 + 8] = o1;
  }
}

// ------- aggregation, HC=64 + FUSED final linear: p[i] = (agg_i + b2) . lin_w (fp8 gather) ------
__global__ void agg64_kernel(const unsigned char* __restrict__ h, const int* __restrict__ offsets,
                             const int* __restrict__ src_sorted, const float* __restrict__ es,
                             const float* __restrict__ ed, const float* __restrict__ bias,
                             const float* __restrict__ lin_w, float* __restrict__ pnode, int n) {
  int node = blockIdx.x * (blockDim.x >> 6) + (threadIdx.x >> 6);
  int lane = threadIdx.x & 63;
  if (node >= n) return;
  int grp = lane >> 3;
  int l8 = lane & 7;
  float myEd = ed[node];
  int off = offsets[node];
  int deg = offsets[node + 1] - off;
  float acc[8] = {};
  float sw = 0.f;
  int j = 0;
  for (; j + 8 <= deg; j += 8) {
    int s = src_sorted[off + j + grp];
    float w = fexp2(lrelu(es[s] + myEd));
    sw += w;
    u32x2 u = *(const u32x2*)&h[(size_t)s * 64 + l8 * 8];
    float f[8];
    dec8(u.x, u.y, f);
#pragma unroll
    for (int k = 0; k < 8; k++) acc[k] += w * f[k];
  }
  if (j < deg && grp < deg - j) {
    int s = src_sorted[off + j + grp];
    float w = fexp2(lrelu(es[s] + myEd));
    sw += w;
    u32x2 u = *(const u32x2*)&h[(size_t)s * 64 + l8 * 8];
    float f[8];
    dec8(u.x, u.y, f);
#pragma unroll
    for (int k = 0; k < 8; k++) acc[k] += w * f[k];
  }
#pragma unroll
  for (int o = 8; o < 64; o <<= 1) {
    sw += __shfl_xor(sw, o);
#pragma unroll
    for (int k = 0; k < 8; k++) acc[k] += __shfl_xor(acc[k], o);
  }
  float invS = 1.0f / (sw + 1e-16f);
  float p = 0.f;
#pragma unroll
  for (int k = 0; k < 8; k++) {
    int c = (k & 3) * 16 + l8 * 2 + (k >> 2);  // cmap(l8*8+k)
    p += (acc[k] * invS + bias[c]) * lin_w[c];
  }
#pragma unroll
  for (int o = 1; o < 8; o <<= 1) p += __shfl_xor(p, o);
  if (lane == 0) pnode[node] = p;
}

// ---------------- FUSED pool+final: block g binary-searches its segment, reduces, writes out ----
static __device__ __forceinline__ int lowerb(const int* __restrict__ a, int n, int key) {
  int lo = 0, hi = n;
  while (lo < hi) {
    int mid = (lo + hi) >> 1;
    if (a[mid] < key) lo = mid + 1; else hi = mid;
  }
  return lo;
}

__global__ void poolfinal_kernel(const float* __restrict__ pnode, const int* __restrict__ batch,
                                 const float* __restrict__ lin_b, float* __restrict__ out, int n) {
  __shared__ float ws[4];
  int g = blockIdx.x;
  int start = lowerb(batch, n, g);
  int end = lowerb(batch, n, g + 1);
  float acc = 0.f;
  for (int i = start + threadIdx.x; i < end; i += 256) acc += pnode[i];
  for (int o = 32; o > 0; o >>= 1) acc += __shfl_down(acc, o);
  if ((threadIdx.x & 63) == 0) ws[threadIdx.x >> 6] = acc;
  __syncthreads();
  if (threadIdx.x == 0) {
    float total = ws[0] + ws[1] + ws[2] + ws[3];
    out[g] = total / fmaxf((float)(end - start), 1.0f) + lin_b[0];
  }
}

extern "C" void kernel_launch(void* const* d_in, const int* in_sizes, int n_in, void* d_out,
                              int out_size, void* d_ws, size_t ws_size, hipStream_t stream) {
  const float* x = (const float*)d_in[0];
  const int* edge_index = (const int*)d_in[1];
  const int* batch = (const int*)d_in[2];
  const float* W0 = (const float*)d_in[3];
  const float* a_src0 = (const float*)d_in[4];
  const float* a_dst0 = (const float*)d_in[5];
  const float* b0 = (const float*)d_in[6];
  const float* W1 = (const float*)d_in[7];
  const float* a_src1 = (const float*)d_in[8];
  const float* a_dst1 = (const float*)d_in[9];
  const float* b1 = (const float*)d_in[10];
  const float* W2 = (const float*)d_in[11];
  const float* a_src2 = (const float*)d_in[12];
  const float* a_dst2 = (const float*)d_in[13];
  const float* b2 = (const float*)d_in[14];
  const float* lin_w = (const float*)d_in[15];
  const float* lin_b = (const float*)d_in[16];
  float* out = (float*)d_out;

  const int N = in_sizes[2];      // 50000
  const int E = in_sizes[1] / 2;  // 800000
  const int EE = E + N;
  const int G = 64;
  const int FIN = in_sizes[0] / N;  // 128

  const int* srcArr = edge_index;
  const int* dstArr = edge_index + E;

  // workspace carve (256B aligned)
  size_t off = 0;
  auto alloc = [&](size_t bytes) -> void* {
    off = (off + 255) & ~(size_t)255;
    void* p = (char*)d_ws + off;
    off += bytes;
    return p;
  };
  unsigned char* hA = (unsigned char*)alloc((size_t)N * 256);  // GEMM out, fp8 permuted
  __bf16* hB = (__bf16*)alloc((size_t)N * 256 * 2);            // aggregate out, bf16 permuted
  unsigned char* h2 = (unsigned char*)alloc((size_t)N * 64);   // layer2 GEMM out, fp8 permuted
  float* pnode = (float*)alloc((size_t)N * 4);
  __bf16* Bt0 = (__bf16*)alloc((size_t)256 * FIN * 2);
  __bf16* Bt1 = (__bf16*)alloc((size_t)256 * 256 * 2);
  __bf16* Bt2 = (__bf16*)alloc((size_t)64 * 256 * 2);
  float* es = (float*)alloc((size_t)N * 4 * 4);
  float* ed = (float*)alloc((size_t)N * 4 * 4);
  int* offsets = (int*)alloc((size_t)(N + 1) * 4);
  int* src_sorted = (int*)alloc((size_t)EE * 4);
  int* bucket_cnt = (int*)alloc((size_t)4096 * 4);  // 196 buckets padded to 64B stride
  (void)ws_size;

  int NB = (N + 255) >> 8;  // dst-range buckets (256 nodes each)

  // part[] lives only between gemm_part and bucket_csr; hB is first written later by
  // agg256 -> alias part onto hB (NB*BCAP*4 = 6.4MB << 25.6MB).
  unsigned int* part = (unsigned int*)hB;

  int nwb = (N + 3) / 4;        // aggregate: one node per wave, 4 waves/block
  int gmx = (N + 63) / 64;      // GEMM M-blocks (64 rows each)
  int nA = (EE + 4095) / 4096;  // partition blocks (4096 edges each)

  // ---- prep (weight transposes, zero bucket counters) ----
  prep_kernel<<<576 + 16, 256, 0, stream>>>(W0, Bt0, W1, Bt1, W2, Bt2, FIN, bucket_cnt, 4096);

  // ---- layer-0 GEMM (reads f32 x directly, cvt in-register) + edge bucket-partition ----
  gemm_part_kernel<128, 4><<<gmx + nA, 256, 0, stream>>>(
      x, Bt0, a_src0, a_dst0, hA, es, ed, N, gmx, srcArr, dstArr, bucket_cnt, part, E, EE, N);

  // ---- per-bucket CSR finalize ----
  bucket_csr_kernel<<<NB, 1024, 0, stream>>>(part, bucket_cnt, offsets, src_sorted, N, EE);

  // ---- layer 0 aggregate ----
  agg256_kernel<<<nwb, 256, 0, stream>>>(hA, offsets, src_sorted, es, ed, b0, hB, N);

  // ---- layer 1: 256 -> 4x64 concat, relu ----
  gemm2_kernel<256, 4><<<gmx, 256, 0, stream>>>(hB, Bt1, a_src1, a_dst1, hA, es, ed, N);
  agg256_kernel<<<nwb, 256, 0, stream>>>(hA, offsets, src_sorted, es, ed, b1, hB, N);

  // ---- layer 2: 256 -> 1x64, single head; final linear fused into aggregate ----
  gemm2_kernel<256, 1><<<gmx, 256, 0, stream>>>(hB, Bt2, a_src2, a_dst2, h2, es, ed, N);
  agg64_kernel<<<nwb, 256, 0, stream>>>(h2, offsets, src_sorted, es, ed, b2, lin_w, pnode, N);

  // ---- fused global mean pool + bias (binary-search segments) ----
  poolfinal_kernel<<<G, 256, 0, stream>>>(pnode, batch, lin_b, out, N);
}

// Round 6
// 281.183 us; speedup vs baseline: 1.6590x; 1.0016x over previous
//
#include <hip/hip_runtime.h>
#include <math.h>

typedef __bf16 bf16x8 __attribute__((ext_vector_type(8)));
typedef __bf16 bf16x4 __attribute__((ext_vector_type(4)));
typedef float f32x4 __attribute__((ext_vector_type(4)));
typedef float f32x2 __attribute__((ext_vector_type(2)));
typedef unsigned int u32x2 __attribute__((ext_vector_type(2)));
typedef unsigned int u32x4 __attribute__((ext_vector_type(4)));

#define LOG2E 1.4426950408889634f
#define BCAP 8192  // per-bucket region capacity in part[] (expected load ~4340, 60-sigma margin)

static __device__ __forceinline__ float lrelu(float e) { return e > 0.0f ? e : 0.2f * e; }
static __device__ __forceinline__ float fexp2(float x) { return __builtin_amdgcn_exp2f(x); }

// permuted-position -> true-channel map: p = blk*64 + l16*4 + ng  <->  c = blk*64 + ng*16 + l16
static __device__ __forceinline__ int cmap(int p) {
  return (p & ~63) + (p & 3) * 16 + ((p & 63) >> 2);
}

// ---------------- prep: weight transposes, zero bucket counters ----------------
__global__ void prep_kernel(const float* __restrict__ W0, __bf16* __restrict__ Bt0,
                            const float* __restrict__ W1, __bf16* __restrict__ Bt1,
                            const float* __restrict__ W2, __bf16* __restrict__ Bt2, int FIN,
                            int* __restrict__ cnt, int n) {
  int b = blockIdx.x;
  if (b < 256) {  // Bt0[256][FIN] = W0^T (x unpermuted)
    for (int k = threadIdx.x; k < FIN; k += 256) Bt0[b * FIN + k] = (__bf16)W0[k * 256 + b];
    return;
  }
  b -= 256;
  if (b < 256) {  // Bt1[n][p] = W1[cmap(p)][n]
    int k = threadIdx.x;
    Bt1[b * 256 + k] = (__bf16)W1[cmap(k) * 256 + b];
    return;
  }
  b -= 256;
  if (b < 64) {  // Bt2[n][p] = W2[cmap(p)][n]
    int k = threadIdx.x;
    Bt2[b * 256 + k] = (__bf16)W2[cmap(k) * 64 + b];
    return;
  }
  b -= 64;
  // zero bucket counters (re-init every launch: harness re-poisons d_ws)
  int i = b * 256 + threadIdx.x;
  if (i < n) cnt[i] = 0;
}

// ------- FUSED: layer-0 GEMM (f32 A read, in-register bf16 cvt) + bucket-partition --------
template <int K, int NT>
__global__ __launch_bounds__(256) void gemm_part_kernel(
    const float* __restrict__ A, const __bf16* __restrict__ Bt,
    const float* __restrict__ a_src, const float* __restrict__ a_dst,
    unsigned char* __restrict__ C, float* __restrict__ es, float* __restrict__ ed, int M,
    int gmx, const int* __restrict__ srcE, const int* __restrict__ dstE,
    int* __restrict__ bucket_cnt, unsigned int* __restrict__ part, int E, int EE, int n) {
  constexpr int Nc = NT * 64;
  constexpr int H = NT;
  constexpr int KS = K / 32;
  __shared__ __bf16 Bs[2][NT * 64][40];
  if ((int)blockIdx.x >= gmx) {
    int tid = threadIdx.x;
    int* hist = (int*)&Bs[0][0][0];  // 256 ints
    int* gbase = hist + 256;         // 256 ints (2KB total, fits in Bs)
    hist[tid] = 0;
    __syncthreads();
    int ab = ((int)blockIdx.x - gmx) * 4096;
    int sv[16], dv[16];
#pragma unroll
    for (int t = 0; t < 16; t++) {
      int e = ab + t * 256 + tid;
      if (e < EE) {
        if (e < E) { sv[t] = srcE[e]; dv[t] = dstE[e]; }
        else { sv[t] = dv[t] = e - E; }  // self-loops
      } else { sv[t] = -1; dv[t] = 0; }
    }
    int lr[16];
#pragma unroll
    for (int t = 0; t < 16; t++)
      if (sv[t] >= 0) lr[t] = atomicAdd(&hist[dv[t] >> 8], 1);
    __syncthreads();
    int NB = (n + 255) >> 8;
    gbase[tid] = (tid < NB && hist[tid] > 0) ? atomicAdd(&bucket_cnt[tid * 16], hist[tid]) : 0;
    __syncthreads();
#pragma unroll
    for (int t = 0; t < 16; t++)
      if (sv[t] >= 0) {
        int bk = dv[t] >> 8;
        part[(size_t)bk * BCAP + gbase[bk] + lr[t]] =
            (unsigned int)sv[t] | ((unsigned int)(dv[t] & 255) << 24);  // N < 2^24
      }
    return;
  }
  int bid = blockIdx.x;
  int tid = threadIdx.x;
  int wave = tid >> 6;
  int lane = tid & 63;
  int quad = lane >> 4;
  int l16 = lane & 15;
  int rowBase = bid * 64 + wave * 16;
  f32x4 acc[NT * 4] = {};
  int arow = rowBase + l16;
  arow = (arow < M) ? arow : (M - 1);
  const float* Aptr = &A[(size_t)arow * K + quad * 8];
  int sr = tid >> 2;
  int sc = (tid & 3) * 8;
  // prefetch whole per-lane A slice, converting f32 -> bf16 in-register
  bf16x8 af[KS];
#pragma unroll
  for (int s = 0; s < KS; s++) {
    f32x4 lo = *(const f32x4*)&Aptr[s * 32];
    f32x4 hi = *(const f32x4*)&Aptr[s * 32 + 4];
    bf16x8 t;
    t[0] = (__bf16)lo.x; t[1] = (__bf16)lo.y; t[2] = (__bf16)lo.z; t[3] = (__bf16)lo.w;
    t[4] = (__bf16)hi.x; t[5] = (__bf16)hi.y; t[6] = (__bf16)hi.z; t[7] = (__bf16)hi.w;
    af[s] = t;
  }
#pragma unroll
  for (int it = 0; it < NT; it++) {
    int r = it * 64 + sr;
    *(bf16x8*)&Bs[0][r][sc] = *(const bf16x8*)&Bt[(size_t)r * K + sc];
  }
  __syncthreads();
#pragma unroll
  for (int s = 0; s < KS; s++) {
    int cur = s & 1;
    if (s + 1 < KS) {
#pragma unroll
      for (int it = 0; it < NT; it++) {
        int r = it * 64 + sr;
        *(bf16x8*)&Bs[cur ^ 1][r][sc] = *(const bf16x8*)&Bt[(size_t)r * K + (s + 1) * 32 + sc];
      }
    }
#pragma unroll
    for (int ng = 0; ng < NT * 4; ng++) {
      bf16x8 b = *(const bf16x8*)&Bs[cur][ng * 16 + l16][quad * 8];
      acc[ng] = __builtin_amdgcn_mfma_f32_16x16x32_bf16(af[s], b, acc[ng], 0, 0, 0);
    }
    __syncthreads();
  }
  float asv[NT * 4], adv[NT * 4];
#pragma unroll
  for (int ng = 0; ng < NT * 4; ng++) {
    int c = (ng >> 2) * 64 + (ng & 3) * 16 + l16;
    asv[ng] = a_src[c];
    adv[ng] = a_dst[c];
  }
#pragma unroll
  for (int r = 0; r < 4; r++) {
    int row = rowBase + quad * 4 + r;
#pragma unroll
    for (int h = 0; h < H; h++) {
      float ss = 0.f, sd = 0.f;
#pragma unroll
      for (int g = 0; g < 4; g++) {
        float hv = acc[h * 4 + g][r];
        ss += hv * asv[h * 4 + g];
        sd += hv * adv[h * 4 + g];
      }
#pragma unroll
      for (int o = 1; o < 16; o <<= 1) {
        ss += __shfl_xor(ss, o);
        sd += __shfl_xor(sd, o);
      }
      if (row < M) {
        if (l16 == 0) {
          es[row * H + h] = ss * LOG2E;  // pre-scaled for exp2 in aggregate
          ed[row * H + h] = sd * LOG2E;
        }
        unsigned int pk = 0;
        pk = __builtin_amdgcn_cvt_pk_fp8_f32(acc[h * 4 + 0][r], acc[h * 4 + 1][r], pk, false);
        pk = __builtin_amdgcn_cvt_pk_fp8_f32(acc[h * 4 + 2][r], acc[h * 4 + 3][r], pk, true);
        *(unsigned int*)&C[(size_t)row * Nc + h * 64 + l16 * 4] = pk;
      }
    }
  }
}

// ------- per-bucket CSR finalize: one block per 256-node bucket, all ranks in LDS --------
__global__ __launch_bounds__(1024) void bucket_csr_kernel(
    const unsigned int* __restrict__ part, const int* __restrict__ bucket_cnt,
    int* __restrict__ offsets, int* __restrict__ src_sorted, int n, int EE) {
  __shared__ int sc[256];
  __shared__ int excl[256];
  __shared__ int run[256];
  int tid = threadIdx.x;
  int b = blockIdx.x;
  int NB = (n + 255) >> 8;
  if (tid < 256) sc[tid] = (tid < NB) ? bucket_cnt[tid * 16] : 0;
  __syncthreads();
  for (int d = 1; d < 256; d <<= 1) {
    int t = 0;
    if (tid < 256 && tid >= d) t = sc[tid - d];
    __syncthreads();
    if (tid < 256) sc[tid] += t;
    __syncthreads();
  }
  int base = (b == 0) ? 0 : sc[b - 1];
  int cb = sc[b] - base;
  const unsigned int* mypart = part + (size_t)b * BCAP;
  if (tid < 256) run[tid] = 0;
  __syncthreads();
  for (int i = tid; i < cb; i += 1024) atomicAdd(&run[mypart[i] >> 24], 1);
  __syncthreads();
  int myc = (tid < 256) ? run[tid] : 0;
  if (tid < 256) sc[tid] = myc;
  __syncthreads();
  for (int d = 1; d < 256; d <<= 1) {
    int t = 0;
    if (tid < 256 && tid >= d) t = sc[tid - d];
    __syncthreads();
    if (tid < 256) sc[tid] += t;
    __syncthreads();
  }
  if (tid < 256) {
    excl[tid] = sc[tid] - myc;
    int node = b * 256 + tid;
    if (node < n) offsets[node] = base + excl[tid];
    run[tid] = 0;
  }
  if (b == 0 && tid == 0) offsets[n] = EE;
  __syncthreads();
  for (int i = tid; i < cb; i += 1024) {
    unsigned int p = mypart[i];
    int j = p >> 24;
    int r = atomicAdd(&run[j], 1);
    src_sorted[base + excl[j] + r] = (int)(p & 0xFFFFFFu);
  }
}

// plain single-pass GEMM (layers 1/2): full-A prefetch + double-buffered Bs
template <int K, int NT>
__global__ __launch_bounds__(256) void gemm2_kernel(const __bf16* __restrict__ A,
                                                    const __bf16* __restrict__ Bt,
                                                    const float* __restrict__ a_src,
                                                    const float* __restrict__ a_dst,
                                                    unsigned char* __restrict__ C,
                                                    float* __restrict__ es,
                                                    float* __restrict__ ed, int M) {
  constexpr int Nc = NT * 64;
  constexpr int H = NT;
  constexpr int KS = K / 32;
  __shared__ __bf16 Bs[2][NT * 64][40];
  int tid = threadIdx.x;
  int wave = tid >> 6;
  int lane = tid & 63;
  int quad = lane >> 4;
  int l16 = lane & 15;
  int rowBase = blockIdx.x * 64 + wave * 16;
  f32x4 acc[NT * 4] = {};
  int arow = rowBase + l16;
  arow = (arow < M) ? arow : (M - 1);
  const __bf16* Aptr = &A[(size_t)arow * K + quad * 8];
  int sr = tid >> 2;
  int sc = (tid & 3) * 8;
  bf16x8 af[KS];
#pragma unroll
  for (int s = 0; s < KS; s++) af[s] = *(const bf16x8*)&Aptr[s * 32];
#pragma unroll
  for (int it = 0; it < NT; it++) {
    int r = it * 64 + sr;
    *(bf16x8*)&Bs[0][r][sc] = *(const bf16x8*)&Bt[(size_t)r * K + sc];
  }
  __syncthreads();
#pragma unroll
  for (int s = 0; s < KS; s++) {
    int cur = s & 1;
    if (s + 1 < KS) {
#pragma unroll
      for (int it = 0; it < NT; it++) {
        int r = it * 64 + sr;
        *(bf16x8*)&Bs[cur ^ 1][r][sc] = *(const bf16x8*)&Bt[(size_t)r * K + (s + 1) * 32 + sc];
      }
    }
#pragma unroll
    for (int ng = 0; ng < NT * 4; ng++) {
      bf16x8 b = *(const bf16x8*)&Bs[cur][ng * 16 + l16][quad * 8];
      acc[ng] = __builtin_amdgcn_mfma_f32_16x16x32_bf16(af[s], b, acc[ng], 0, 0, 0);
    }
    __syncthreads();
  }
  float asv[NT * 4], adv[NT * 4];
#pragma unroll
  for (int ng = 0; ng < NT * 4; ng++) {
    int c = (ng >> 2) * 64 + (ng & 3) * 16 + l16;
    asv[ng] = a_src[c];
    adv[ng] = a_dst[c];
  }
#pragma unroll
  for (int r = 0; r < 4; r++) {
    int row = rowBase + quad * 4 + r;
#pragma unroll
    for (int h = 0; h < H; h++) {
      float ss = 0.f, sd = 0.f;
#pragma unroll
      for (int g = 0; g < 4; g++) {
        float hv = acc[h * 4 + g][r];
        ss += hv * asv[h * 4 + g];
        sd += hv * adv[h * 4 + g];
      }
#pragma unroll
      for (int o = 1; o < 16; o <<= 1) {
        ss += __shfl_xor(ss, o);
        sd += __shfl_xor(sd, o);
      }
      if (row < M) {
        if (l16 == 0) {
          es[row * H + h] = ss * LOG2E;
          ed[row * H + h] = sd * LOG2E;
        }
        unsigned int pk = 0;
        pk = __builtin_amdgcn_cvt_pk_fp8_f32(acc[h * 4 + 0][r], acc[h * 4 + 1][r], pk, false);
        pk = __builtin_amdgcn_cvt_pk_fp8_f32(acc[h * 4 + 2][r], acc[h * 4 + 3][r], pk, true);
        *(unsigned int*)&C[(size_t)row * Nc + h * 64 + l16 * 4] = pk;
      }
    }
  }
}

// ------- aggregation, HC=256: whole index list in registers (1 vector load), 1-deep
// software pipeline over es+h gathers. 4 edges/wave via quads, 8 edges per iteration. -------
__global__ void agg256_kernel(const unsigned char* __restrict__ h, const int* __restrict__ offsets,
                              const int* __restrict__ src_sorted, const float* __restrict__ es,
                              const float* __restrict__ ed, const float* __restrict__ bias,
                              __bf16* __restrict__ out, int n) {
  int node = blockIdx.x * (blockDim.x >> 6) + (threadIdx.x >> 6);
  int lane = threadIdx.x & 63;
  if (node >= n) return;
  int quad = lane >> 4;
  int l16 = lane & 15;  // positions l16*16 .. +16
  int hd = l16 >> 2;
  float myEd = ed[node * 4 + hd];
  int off = offsets[node];
  int deg = offsets[node + 1] - off;
  // bulk index load: lane i holds src_sorted[off+i] (covers deg<=64; Poisson(17) => ~always)
  int idxr = (lane < deg) ? src_sorted[off + lane] : 0;
  float acc[16] = {};
  float sw = 0.f;
  int npre = (deg < 64 ? deg : 64) & ~7;  // full-8 groups served from registers
  int j = 0;
  // stage A prefetch (indices from registers via shfl; es+h issued immediately)
  int sA0 = 0, sA1 = 0;
  float eA0 = 0.f, eA1 = 0.f;
  u32x4 uA0 = {}, uA1 = {};
  if (j + 8 <= npre) {
    sA0 = __shfl(idxr, j + quad);
    sA1 = __shfl(idxr, j + 4 + quad);
    eA0 = es[sA0 * 4 + hd];
    eA1 = es[sA1 * 4 + hd];
    uA0 = *(const u32x4*)&h[(size_t)sA0 * 256 + l16 * 16];
    uA1 = *(const u32x4*)&h[(size_t)sA1 * 256 + l16 * 16];
  }
  while (j + 8 <= npre) {
    int jn = j + 8;
    // stage B prefetch (next 8 edges) before consuming stage A
    int sB0 = 0, sB1 = 0;
    float eB0 = 0.f, eB1 = 0.f;
    u32x4 uB0 = {}, uB1 = {};
    if (jn + 8 <= npre) {
      sB0 = __shfl(idxr, jn + quad);
      sB1 = __shfl(idxr, jn + 4 + quad);
      eB0 = es[sB0 * 4 + hd];
      eB1 = es[sB1 * 4 + hd];
      uB0 = *(const u32x4*)&h[(size_t)sB0 * 256 + l16 * 16];
      uB1 = *(const u32x4*)&h[(size_t)sB1 * 256 + l16 * 16];
    }
    // consume stage A
    float w0 = fexp2(lrelu(eA0 + myEd));
    float w1 = fexp2(lrelu(eA1 + myEd));
    sw += w0 + w1;
#pragma unroll
    for (int i = 0; i < 4; i++) {
      f32x2 a = __builtin_amdgcn_cvt_pk_f32_fp8(uA0[i], false);
      f32x2 b = __builtin_amdgcn_cvt_pk_f32_fp8(uA0[i], true);
      acc[i * 4 + 0] += w0 * a.x;
      acc[i * 4 + 1] += w0 * a.y;
      acc[i * 4 + 2] += w0 * b.x;
      acc[i * 4 + 3] += w0 * b.y;
    }
#pragma unroll
    for (int i = 0; i < 4; i++) {
      f32x2 a = __builtin_amdgcn_cvt_pk_f32_fp8(uA1[i], false);
      f32x2 b = __builtin_amdgcn_cvt_pk_f32_fp8(uA1[i], true);
      acc[i * 4 + 0] += w1 * a.x;
      acc[i * 4 + 1] += w1 * a.y;
      acc[i * 4 + 2] += w1 * b.x;
      acc[i * 4 + 3] += w1 * b.y;
    }
    eA0 = eB0; eA1 = eB1; uA0 = uB0; uA1 = uB1;
    j = jn;
  }
  for (; j < deg; j += 4) {  // tail (and rare deg>64 overflow): 1 edge per quad, direct loads
    if (quad < deg - j) {
      int s = src_sorted[off + j + quad];
      float w = fexp2(lrelu(es[s * 4 + hd] + myEd));
      sw += w;
      u32x4 u = *(const u32x4*)&h[(size_t)s * 256 + l16 * 16];
#pragma unroll
      for (int i = 0; i < 4; i++) {
        f32x2 a = __builtin_amdgcn_cvt_pk_f32_fp8(u[i], false);
        f32x2 b = __builtin_amdgcn_cvt_pk_f32_fp8(u[i], true);
        acc[i * 4 + 0] += w * a.x;
        acc[i * 4 + 1] += w * a.y;
        acc[i * 4 + 2] += w * b.x;
        acc[i * 4 + 3] += w * b.y;
      }
    }
  }
  sw += __shfl_xor(sw, 16);
  sw += __shfl_xor(sw, 32);
#pragma unroll
  for (int k = 0; k < 16; k++) {
    acc[k] += __shfl_xor(acc[k], 16);
    acc[k] += __shfl_xor(acc[k], 32);
  }
  float invS = 1.0f / (sw + 1e-16f);
  if (quad == 0) {
    bf16x8 o0, o1;
#pragma unroll
    for (int k = 0; k < 16; k++) {
      int c = hd * 64 + (k & 3) * 16 + (l16 & 3) * 4 + (k >> 2);  // cmap(l16*16+k)
      float v = fmaxf(acc[k] * invS + bias[c], 0.f);
      if (k < 8) o0[k] = (__bf16)v; else o1[k - 8] = (__bf16)v;
    }
    *(bf16x8*)&out[(size_t)node * 256 + l16 * 16] = o0;
    *(bf16x8*)&out[(size_t)node * 256 + l16 * 16 + 8] = o1;
  }
}

// ------- aggregation, HC=64 + FUSED final linear, register-index + pipelined gathers ------
__global__ void agg64_kernel(const unsigned char* __restrict__ h, const int* __restrict__ offsets,
                             const int* __restrict__ src_sorted, const float* __restrict__ es,
                             const float* __restrict__ ed, const float* __restrict__ bias,
                             const float* __restrict__ lin_w, float* __restrict__ pnode, int n) {
  int node = blockIdx.x * (blockDim.x >> 6) + (threadIdx.x >> 6);
  int lane = threadIdx.x & 63;
  if (node >= n) return;
  int grp = lane >> 3;
  int l8 = lane & 7;
  float myEd = ed[node];
  int off = offsets[node];
  int deg = offsets[node + 1] - off;
  int idxr = (lane < deg) ? src_sorted[off + lane] : 0;
  float acc[8] = {};
  float sw = 0.f;
  int npre = (deg < 64 ? deg : 64) & ~7;
  int j = 0;
  int sA = 0;
  float eA = 0.f;
  u32x2 uA = {};
  if (j + 8 <= npre) {
    sA = __shfl(idxr, j + grp);
    eA = es[sA];
    uA = *(const u32x2*)&h[(size_t)sA * 64 + l8 * 8];
  }
  while (j + 8 <= npre) {
    int jn = j + 8;
    int sB = 0;
    float eB = 0.f;
    u32x2 uB = {};
    if (jn + 8 <= npre) {
      sB = __shfl(idxr, jn + grp);
      eB = es[sB];
      uB = *(const u32x2*)&h[(size_t)sB * 64 + l8 * 8];
    }
    float w = fexp2(lrelu(eA + myEd));
    sw += w;
    {
      f32x2 a = __builtin_amdgcn_cvt_pk_f32_fp8(uA.x, false);
      f32x2 b = __builtin_amdgcn_cvt_pk_f32_fp8(uA.x, true);
      f32x2 c = __builtin_amdgcn_cvt_pk_f32_fp8(uA.y, false);
      f32x2 d = __builtin_amdgcn_cvt_pk_f32_fp8(uA.y, true);
      acc[0] += w * a.x; acc[1] += w * a.y; acc[2] += w * b.x; acc[3] += w * b.y;
      acc[4] += w * c.x; acc[5] += w * c.y; acc[6] += w * d.x; acc[7] += w * d.y;
    }
    eA = eB; uA = uB;
    j = jn;
  }
  for (; j < deg; j += 8) {  // tail (and rare deg>64 overflow)
    if (grp < deg - j) {
      int s = src_sorted[off + j + grp];
      float w = fexp2(lrelu(es[s] + myEd));
      sw += w;
      u32x2 u = *(const u32x2*)&h[(size_t)s * 64 + l8 * 8];
      f32x2 a = __builtin_amdgcn_cvt_pk_f32_fp8(u.x, false);
      f32x2 b = __builtin_amdgcn_cvt_pk_f32_fp8(u.x, true);
      f32x2 c = __builtin_amdgcn_cvt_pk_f32_fp8(u.y, false);
      f32x2 d = __builtin_amdgcn_cvt_pk_f32_fp8(u.y, true);
      acc[0] += w * a.x; acc[1] += w * a.y; acc[2] += w * b.x; acc[3] += w * b.y;
      acc[4] += w * c.x; acc[5] += w * c.y; acc[6] += w * d.x; acc[7] += w * d.y;
    }
  }
#pragma unroll
  for (int o = 8; o < 64; o <<= 1) {
    sw += __shfl_xor(sw, o);
#pragma unroll
    for (int k = 0; k < 8; k++) acc[k] += __shfl_xor(acc[k], o);
  }
  float invS = 1.0f / (sw + 1e-16f);
  float p = 0.f;
#pragma unroll
  for (int k = 0; k < 8; k++) {
    int c = (k & 3) * 16 + l8 * 2 + (k >> 2);  // cmap(l8*8+k)
    p += (acc[k] * invS + bias[c]) * lin_w[c];
  }
#pragma unroll
  for (int o = 1; o < 8; o <<= 1) p += __shfl_xor(p, o);
  if (lane == 0) pnode[node] = p;
}

// ---------------- FUSED pool+final: block g binary-searches its segment, reduces, writes out ----
static __device__ __forceinline__ int lowerb(const int* __restrict__ a, int n, int key) {
  int lo = 0, hi = n;
  while (lo < hi) {
    int mid = (lo + hi) >> 1;
    if (a[mid] < key) lo = mid + 1; else hi = mid;
  }
  return lo;
}

__global__ void poolfinal_kernel(const float* __restrict__ pnode, const int* __restrict__ batch,
                                 const float* __restrict__ lin_b, float* __restrict__ out, int n) {
  __shared__ float ws[4];
  int g = blockIdx.x;
  int start = lowerb(batch, n, g);
  int end = lowerb(batch, n, g + 1);
  float acc = 0.f;
  for (int i = start + threadIdx.x; i < end; i += 256) acc += pnode[i];
  for (int o = 32; o > 0; o >>= 1) acc += __shfl_down(acc, o);
  if ((threadIdx.x & 63) == 0) ws[threadIdx.x >> 6] = acc;
  __syncthreads();
  if (threadIdx.x == 0) {
    float total = ws[0] + ws[1] + ws[2] + ws[3];
    out[g] = total / fmaxf((float)(end - start), 1.0f) + lin_b[0];
  }
}

extern "C" void kernel_launch(void* const* d_in, const int* in_sizes, int n_in, void* d_out,
                              int out_size, void* d_ws, size_t ws_size, hipStream_t stream) {
  const float* x = (const float*)d_in[0];
  const int* edge_index = (const int*)d_in[1];
  const int* batch = (const int*)d_in[2];
  const float* W0 = (const float*)d_in[3];
  const float* a_src0 = (const float*)d_in[4];
  const float* a_dst0 = (const float*)d_in[5];
  const float* b0 = (const float*)d_in[6];
  const float* W1 = (const float*)d_in[7];
  const float* a_src1 = (const float*)d_in[8];
  const float* a_dst1 = (const float*)d_in[9];
  const float* b1 = (const float*)d_in[10];
  const float* W2 = (const float*)d_in[11];
  const float* a_src2 = (const float*)d_in[12];
  const float* a_dst2 = (const float*)d_in[13];
  const float* b2 = (const float*)d_in[14];
  const float* lin_w = (const float*)d_in[15];
  const float* lin_b = (const float*)d_in[16];
  float* out = (float*)d_out;

  const int N = in_sizes[2];      // 50000
  const int E = in_sizes[1] / 2;  // 800000
  const int EE = E + N;
  const int G = 64;
  const int FIN = in_sizes[0] / N;  // 128

  const int* srcArr = edge_index;
  const int* dstArr = edge_index + E;

  // workspace carve (256B aligned)
  size_t off = 0;
  auto alloc = [&](size_t bytes) -> void* {
    off = (off + 255) & ~(size_t)255;
    void* p = (char*)d_ws + off;
    off += bytes;
    return p;
  };
  unsigned char* hA = (unsigned char*)alloc((size_t)N * 256);  // GEMM out, fp8 permuted
  __bf16* hB = (__bf16*)alloc((size_t)N * 256 * 2);            // aggregate out, bf16 permuted
  unsigned char* h2 = (unsigned char*)alloc((size_t)N * 64);   // layer2 GEMM out, fp8 permuted
  float* pnode = (float*)alloc((size_t)N * 4);
  __bf16* Bt0 = (__bf16*)alloc((size_t)256 * FIN * 2);
  __bf16* Bt1 = (__bf16*)alloc((size_t)256 * 256 * 2);
  __bf16* Bt2 = (__bf16*)alloc((size_t)64 * 256 * 2);
  float* es = (float*)alloc((size_t)N * 4 * 4);
  float* ed = (float*)alloc((size_t)N * 4 * 4);
  int* offsets = (int*)alloc((size_t)(N + 1) * 4);
  int* src_sorted = (int*)alloc((size_t)EE * 4);
  int* bucket_cnt = (int*)alloc((size_t)4096 * 4);  // 196 buckets padded to 64B stride
  (void)ws_size;

  int NB = (N + 255) >> 8;  // dst-range buckets (256 nodes each)

  // part[] lives only between gemm_part and bucket_csr; hB is first written later by
  // agg256 -> alias part onto hB (NB*BCAP*4 = 6.4MB << 25.6MB).
  unsigned int* part = (unsigned int*)hB;

  int nwb = (N + 3) / 4;        // aggregate: one node per wave, 4 waves/block
  int gmx = (N + 63) / 64;      // GEMM M-blocks (64 rows each)
  int nA = (EE + 4095) / 4096;  // partition blocks (4096 edges each)

  // ---- prep (weight transposes, zero bucket counters) ----
  prep_kernel<<<576 + 16, 256, 0, stream>>>(W0, Bt0, W1, Bt1, W2, Bt2, FIN, bucket_cnt, 4096);

  // ---- layer-0 GEMM (reads f32 x directly, cvt in-register) + edge bucket-partition ----
  gemm_part_kernel<128, 4><<<gmx + nA, 256, 0, stream>>>(
      x, Bt0, a_src0, a_dst0, hA, es, ed, N, gmx, srcArr, dstArr, bucket_cnt, part, E, EE, N);

  // ---- per-bucket CSR finalize ----
  bucket_csr_kernel<<<NB, 1024, 0, stream>>>(part, bucket_cnt, offsets, src_sorted, N, EE);

  // ---- layer 0 aggregate ----
  agg256_kernel<<<nwb, 256, 0, stream>>>(hA, offsets, src_sorted, es, ed, b0, hB, N);

  // ---- layer 1: 256 -> 4x64 concat, relu ----
  gemm2_kernel<256, 4><<<gmx, 256, 0, stream>>>(hB, Bt1, a_src1, a_dst1, hA, es, ed, N);
  agg256_kernel<<<nwb, 256, 0, stream>>>(hA, offsets, src_sorted, es, ed, b1, hB, N);

  // ---- layer 2: 256 -> 1x64, single head; final linear fused into aggregate ----
  gemm2_kernel<256, 1><<<gmx, 256, 0, stream>>>(hB, Bt2, a_src2, a_dst2, h2, es, ed, N);
  agg64_kernel<<<nwb, 256, 0, stream>>>(h2, offsets, src_sorted, es, ed, b2, lin_w, pnode, N);

  // ---- fused global mean pool + bias (binary-search segments) ----
  poolfinal_kernel<<<G, 256, 0, stream>>>(pnode, batch, lin_b, out, N);
}

// Round 7
// 277.373 us; speedup vs baseline: 1.6818x; 1.0137x over previous
//
#include <hip/hip_runtime.h>
#include <math.h>

typedef __bf16 bf16x8 __attribute__((ext_vector_type(8)));
typedef __bf16 bf16x4 __attribute__((ext_vector_type(4)));
typedef float f32x4 __attribute__((ext_vector_type(4)));
typedef float f32x2 __attribute__((ext_vector_type(2)));
typedef unsigned int u32x2 __attribute__((ext_vector_type(2)));
typedef unsigned int u32x4 __attribute__((ext_vector_type(4)));

#define LOG2E 1.4426950408889634f
#define BCAP 8192  // per-bucket region capacity in part[] (expected load ~4340, 60-sigma margin)

// lrelu(e) == max(e, 0.2e) exactly (e>0: e; e<=0: 0.2e) — 2 VALU ops, bitwise-identical result
static __device__ __forceinline__ float lrelu(float e) { return fmaxf(e, 0.2f * e); }
static __device__ __forceinline__ float fexp2(float x) { return __builtin_amdgcn_exp2f(x); }

// permuted-position -> true-channel map: p = blk*64 + l16*4 + ng  <->  c = blk*64 + ng*16 + l16
static __device__ __forceinline__ int cmap(int p) {
  return (p & ~63) + (p & 3) * 16 + ((p & 63) >> 2);
}

// ---------------- prep: weight transposes, zero bucket counters ----------------
__global__ void prep_kernel(const float* __restrict__ W0, __bf16* __restrict__ Bt0,
                            const float* __restrict__ W1, __bf16* __restrict__ Bt1,
                            const float* __restrict__ W2, __bf16* __restrict__ Bt2, int FIN,
                            int* __restrict__ cnt, int n) {
  int b = blockIdx.x;
  if (b < 256) {  // Bt0[256][FIN] = W0^T (x unpermuted)
    for (int k = threadIdx.x; k < FIN; k += 256) Bt0[b * FIN + k] = (__bf16)W0[k * 256 + b];
    return;
  }
  b -= 256;
  if (b < 256) {  // Bt1[n][p] = W1[cmap(p)][n]
    int k = threadIdx.x;
    Bt1[b * 256 + k] = (__bf16)W1[cmap(k) * 256 + b];
    return;
  }
  b -= 256;
  if (b < 64) {  // Bt2[n][p] = W2[cmap(p)][n]
    int k = threadIdx.x;
    Bt2[b * 256 + k] = (__bf16)W2[cmap(k) * 64 + b];
    return;
  }
  b -= 64;
  // zero bucket counters (re-init every launch: harness re-poisons d_ws)
  int i = b * 256 + threadIdx.x;
  if (i < n) cnt[i] = 0;
}

// ------- FUSED: layer-0 GEMM (f32 A read, in-register bf16 cvt) + bucket-partition --------
template <int K, int NT>
__global__ __launch_bounds__(256) void gemm_part_kernel(
    const float* __restrict__ A, const __bf16* __restrict__ Bt,
    const float* __restrict__ a_src, const float* __restrict__ a_dst,
    unsigned char* __restrict__ C, float* __restrict__ es, float* __restrict__ ed, int M,
    int gmx, const int* __restrict__ srcE, const int* __restrict__ dstE,
    int* __restrict__ bucket_cnt, unsigned int* __restrict__ part, int E, int EE, int n) {
  constexpr int Nc = NT * 64;
  constexpr int H = NT;
  constexpr int KS = K / 32;
  __shared__ __bf16 Bs[2][NT * 64][40];
  if ((int)blockIdx.x >= gmx) {
    int tid = threadIdx.x;
    int* hist = (int*)&Bs[0][0][0];  // 256 ints
    int* gbase = hist + 256;         // 256 ints (2KB total, fits in Bs)
    hist[tid] = 0;
    __syncthreads();
    int ab = ((int)blockIdx.x - gmx) * 4096;
    int sv[16], dv[16];
#pragma unroll
    for (int t = 0; t < 16; t++) {
      int e = ab + t * 256 + tid;
      if (e < EE) {
        if (e < E) { sv[t] = srcE[e]; dv[t] = dstE[e]; }
        else { sv[t] = dv[t] = e - E; }  // self-loops
      } else { sv[t] = -1; dv[t] = 0; }
    }
    int lr[16];
#pragma unroll
    for (int t = 0; t < 16; t++)
      if (sv[t] >= 0) lr[t] = atomicAdd(&hist[dv[t] >> 8], 1);
    __syncthreads();
    int NB = (n + 255) >> 8;
    gbase[tid] = (tid < NB && hist[tid] > 0) ? atomicAdd(&bucket_cnt[tid * 16], hist[tid]) : 0;
    __syncthreads();
#pragma unroll
    for (int t = 0; t < 16; t++)
      if (sv[t] >= 0) {
        int bk = dv[t] >> 8;
        part[(size_t)bk * BCAP + gbase[bk] + lr[t]] =
            (unsigned int)sv[t] | ((unsigned int)(dv[t] & 255) << 24);  // N < 2^24
      }
    return;
  }
  int bid = blockIdx.x;
  int tid = threadIdx.x;
  int wave = tid >> 6;
  int lane = tid & 63;
  int quad = lane >> 4;
  int l16 = lane & 15;
  int rowBase = bid * 64 + wave * 16;
  f32x4 acc[NT * 4] = {};
  int arow = rowBase + l16;
  arow = (arow < M) ? arow : (M - 1);
  const float* Aptr = &A[(size_t)arow * K + quad * 8];
  int sr = tid >> 2;
  int sc = (tid & 3) * 8;
  // prefetch whole per-lane A slice, converting f32 -> bf16 in-register
  bf16x8 af[KS];
#pragma unroll
  for (int s = 0; s < KS; s++) {
    f32x4 lo = *(const f32x4*)&Aptr[s * 32];
    f32x4 hi = *(const f32x4*)&Aptr[s * 32 + 4];
    bf16x8 t;
    t[0] = (__bf16)lo.x; t[1] = (__bf16)lo.y; t[2] = (__bf16)lo.z; t[3] = (__bf16)lo.w;
    t[4] = (__bf16)hi.x; t[5] = (__bf16)hi.y; t[6] = (__bf16)hi.z; t[7] = (__bf16)hi.w;
    af[s] = t;
  }
#pragma unroll
  for (int it = 0; it < NT; it++) {
    int r = it * 64 + sr;
    *(bf16x8*)&Bs[0][r][sc] = *(const bf16x8*)&Bt[(size_t)r * K + sc];
  }
  __syncthreads();
#pragma unroll
  for (int s = 0; s < KS; s++) {
    int cur = s & 1;
    if (s + 1 < KS) {
#pragma unroll
      for (int it = 0; it < NT; it++) {
        int r = it * 64 + sr;
        *(bf16x8*)&Bs[cur ^ 1][r][sc] = *(const bf16x8*)&Bt[(size_t)r * K + (s + 1) * 32 + sc];
      }
    }
#pragma unroll
    for (int ng = 0; ng < NT * 4; ng++) {
      bf16x8 b = *(const bf16x8*)&Bs[cur][ng * 16 + l16][quad * 8];
      acc[ng] = __builtin_amdgcn_mfma_f32_16x16x32_bf16(af[s], b, acc[ng], 0, 0, 0);
    }
    __syncthreads();
  }
  float asv[NT * 4], adv[NT * 4];
#pragma unroll
  for (int ng = 0; ng < NT * 4; ng++) {
    int c = (ng >> 2) * 64 + (ng & 3) * 16 + l16;
    asv[ng] = a_src[c];
    adv[ng] = a_dst[c];
  }
#pragma unroll
  for (int r = 0; r < 4; r++) {
    int row = rowBase + quad * 4 + r;
#pragma unroll
    for (int h = 0; h < H; h++) {
      float ss = 0.f, sd = 0.f;
#pragma unroll
      for (int g = 0; g < 4; g++) {
        float hv = acc[h * 4 + g][r];
        ss += hv * asv[h * 4 + g];
        sd += hv * adv[h * 4 + g];
      }
#pragma unroll
      for (int o = 1; o < 16; o <<= 1) {
        ss += __shfl_xor(ss, o);
        sd += __shfl_xor(sd, o);
      }
      if (row < M) {
        if (l16 == 0) {
          es[row * H + h] = ss * LOG2E;  // pre-scaled for exp2 in aggregate
          ed[row * H + h] = sd * LOG2E;
        }
        unsigned int pk = 0;
        pk = __builtin_amdgcn_cvt_pk_fp8_f32(acc[h * 4 + 0][r], acc[h * 4 + 1][r], pk, false);
        pk = __builtin_amdgcn_cvt_pk_fp8_f32(acc[h * 4 + 2][r], acc[h * 4 + 3][r], pk, true);
        *(unsigned int*)&C[(size_t)row * Nc + h * 64 + l16 * 4] = pk;
      }
    }
  }
}

// ------- per-bucket CSR finalize: one block per 256-node bucket, all ranks in LDS --------
__global__ __launch_bounds__(1024) void bucket_csr_kernel(
    const unsigned int* __restrict__ part, const int* __restrict__ bucket_cnt,
    int* __restrict__ offsets, int* __restrict__ src_sorted, int n, int EE) {
  __shared__ int sc[256];
  __shared__ int excl[256];
  __shared__ int run[256];
  int tid = threadIdx.x;
  int b = blockIdx.x;
  int NB = (n + 255) >> 8;
  if (tid < 256) sc[tid] = (tid < NB) ? bucket_cnt[tid * 16] : 0;
  __syncthreads();
  for (int d = 1; d < 256; d <<= 1) {
    int t = 0;
    if (tid < 256 && tid >= d) t = sc[tid - d];
    __syncthreads();
    if (tid < 256) sc[tid] += t;
    __syncthreads();
  }
  int base = (b == 0) ? 0 : sc[b - 1];
  int cb = sc[b] - base;
  const unsigned int* mypart = part + (size_t)b * BCAP;
  if (tid < 256) run[tid] = 0;
  __syncthreads();
  for (int i = tid; i < cb; i += 1024) atomicAdd(&run[mypart[i] >> 24], 1);
  __syncthreads();
  int myc = (tid < 256) ? run[tid] : 0;
  if (tid < 256) sc[tid] = myc;
  __syncthreads();
  for (int d = 1; d < 256; d <<= 1) {
    int t = 0;
    if (tid < 256 && tid >= d) t = sc[tid - d];
    __syncthreads();
    if (tid < 256) sc[tid] += t;
    __syncthreads();
  }
  if (tid < 256) {
    excl[tid] = sc[tid] - myc;
    int node = b * 256 + tid;
    if (node < n) offsets[node] = base + excl[tid];
    run[tid] = 0;
  }
  if (b == 0 && tid == 0) offsets[n] = EE;
  __syncthreads();
  for (int i = tid; i < cb; i += 1024) {
    unsigned int p = mypart[i];
    int j = p >> 24;
    int r = atomicAdd(&run[j], 1);
    src_sorted[base + excl[j] + r] = (int)(p & 0xFFFFFFu);
  }
}

// plain single-pass GEMM (layers 1/2): full-A prefetch + double-buffered Bs
template <int K, int NT>
__global__ __launch_bounds__(256) void gemm2_kernel(const __bf16* __restrict__ A,
                                                    const __bf16* __restrict__ Bt,
                                                    const float* __restrict__ a_src,
                                                    const float* __restrict__ a_dst,
                                                    unsigned char* __restrict__ C,
                                                    float* __restrict__ es,
                                                    float* __restrict__ ed, int M) {
  constexpr int Nc = NT * 64;
  constexpr int H = NT;
  constexpr int KS = K / 32;
  __shared__ __bf16 Bs[2][NT * 64][40];
  int tid = threadIdx.x;
  int wave = tid >> 6;
  int lane = tid & 63;
  int quad = lane >> 4;
  int l16 = lane & 15;
  int rowBase = blockIdx.x * 64 + wave * 16;
  f32x4 acc[NT * 4] = {};
  int arow = rowBase + l16;
  arow = (arow < M) ? arow : (M - 1);
  const __bf16* Aptr = &A[(size_t)arow * K + quad * 8];
  int sr = tid >> 2;
  int sc = (tid & 3) * 8;
  bf16x8 af[KS];
#pragma unroll
  for (int s = 0; s < KS; s++) af[s] = *(const bf16x8*)&Aptr[s * 32];
#pragma unroll
  for (int it = 0; it < NT; it++) {
    int r = it * 64 + sr;
    *(bf16x8*)&Bs[0][r][sc] = *(const bf16x8*)&Bt[(size_t)r * K + sc];
  }
  __syncthreads();
#pragma unroll
  for (int s = 0; s < KS; s++) {
    int cur = s & 1;
    if (s + 1 < KS) {
#pragma unroll
      for (int it = 0; it < NT; it++) {
        int r = it * 64 + sr;
        *(bf16x8*)&Bs[cur ^ 1][r][sc] = *(const bf16x8*)&Bt[(size_t)r * K + (s + 1) * 32 + sc];
      }
    }
#pragma unroll
    for (int ng = 0; ng < NT * 4; ng++) {
      bf16x8 b = *(const bf16x8*)&Bs[cur][ng * 16 + l16][quad * 8];
      acc[ng] = __builtin_amdgcn_mfma_f32_16x16x32_bf16(af[s], b, acc[ng], 0, 0, 0);
    }
    __syncthreads();
  }
  float asv[NT * 4], adv[NT * 4];
#pragma unroll
  for (int ng = 0; ng < NT * 4; ng++) {
    int c = (ng >> 2) * 64 + (ng & 3) * 16 + l16;
    asv[ng] = a_src[c];
    adv[ng] = a_dst[c];
  }
#pragma unroll
  for (int r = 0; r < 4; r++) {
    int row = rowBase + quad * 4 + r;
#pragma unroll
    for (int h = 0; h < H; h++) {
      float ss = 0.f, sd = 0.f;
#pragma unroll
      for (int g = 0; g < 4; g++) {
        float hv = acc[h * 4 + g][r];
        ss += hv * asv[h * 4 + g];
        sd += hv * adv[h * 4 + g];
      }
#pragma unroll
      for (int o = 1; o < 16; o <<= 1) {
        ss += __shfl_xor(ss, o);
        sd += __shfl_xor(sd, o);
      }
      if (row < M) {
        if (l16 == 0) {
          es[row * H + h] = ss * LOG2E;
          ed[row * H + h] = sd * LOG2E;
        }
        unsigned int pk = 0;
        pk = __builtin_amdgcn_cvt_pk_fp8_f32(acc[h * 4 + 0][r], acc[h * 4 + 1][r], pk, false);
        pk = __builtin_amdgcn_cvt_pk_fp8_f32(acc[h * 4 + 2][r], acc[h * 4 + 3][r], pk, true);
        *(unsigned int*)&C[(size_t)row * Nc + h * 64 + l16 * 4] = pk;
      }
    }
  }
}

// ------- aggregation, HC=256: register index list + 1-deep pipelined gathers.
// 32-bit unsigned byte offsets (saddr-form loads, 1-op addressing). -------
__global__ void agg256_kernel(const unsigned char* __restrict__ h, const int* __restrict__ offsets,
                              const int* __restrict__ src_sorted, const float* __restrict__ es,
                              const float* __restrict__ ed, const float* __restrict__ bias,
                              __bf16* __restrict__ out, int n) {
  int node = blockIdx.x * (blockDim.x >> 6) + (threadIdx.x >> 6);
  int lane = threadIdx.x & 63;
  if (node >= n) return;
  int quad = lane >> 4;
  int l16 = lane & 15;  // positions l16*16 .. +16
  unsigned hd = (unsigned)(l16 >> 2);
  unsigned cOff = (unsigned)(l16 * 16);
  float myEd = ed[node * 4 + hd];
  int off = offsets[node];
  int deg = offsets[node + 1] - off;
  // bulk index load: lane i holds src_sorted[off+i] (covers deg<=64; Poisson(17) => ~always)
  int idxr = (lane < deg) ? src_sorted[off + lane] : 0;
  float acc[16] = {};
  float sw = 0.f;
  int npre = (deg < 64 ? deg : 64) & ~7;  // full-8 groups served from registers
  int j = 0;
  float eA0 = 0.f, eA1 = 0.f;
  u32x4 uA0 = {}, uA1 = {};
  if (j + 8 <= npre) {
    unsigned sA0 = (unsigned)__shfl(idxr, j + quad);
    unsigned sA1 = (unsigned)__shfl(idxr, j + 4 + quad);
    eA0 = es[sA0 * 4u + hd];
    eA1 = es[sA1 * 4u + hd];
    uA0 = *(const u32x4*)(h + (sA0 << 8) + cOff);
    uA1 = *(const u32x4*)(h + (sA1 << 8) + cOff);
  }
  while (j + 8 <= npre) {
    int jn = j + 8;
    float eB0 = 0.f, eB1 = 0.f;
    u32x4 uB0 = {}, uB1 = {};
    if (jn + 8 <= npre) {  // prefetch next 8 edges before consuming current
      unsigned sB0 = (unsigned)__shfl(idxr, jn + quad);
      unsigned sB1 = (unsigned)__shfl(idxr, jn + 4 + quad);
      eB0 = es[sB0 * 4u + hd];
      eB1 = es[sB1 * 4u + hd];
      uB0 = *(const u32x4*)(h + (sB0 << 8) + cOff);
      uB1 = *(const u32x4*)(h + (sB1 << 8) + cOff);
    }
    float w0 = fexp2(lrelu(eA0 + myEd));
    float w1 = fexp2(lrelu(eA1 + myEd));
    sw += w0 + w1;
#pragma unroll
    for (int i = 0; i < 4; i++) {
      f32x2 a = __builtin_amdgcn_cvt_pk_f32_fp8(uA0[i], false);
      f32x2 b = __builtin_amdgcn_cvt_pk_f32_fp8(uA0[i], true);
      acc[i * 4 + 0] += w0 * a.x;
      acc[i * 4 + 1] += w0 * a.y;
      acc[i * 4 + 2] += w0 * b.x;
      acc[i * 4 + 3] += w0 * b.y;
    }
#pragma unroll
    for (int i = 0; i < 4; i++) {
      f32x2 a = __builtin_amdgcn_cvt_pk_f32_fp8(uA1[i], false);
      f32x2 b = __builtin_amdgcn_cvt_pk_f32_fp8(uA1[i], true);
      acc[i * 4 + 0] += w1 * a.x;
      acc[i * 4 + 1] += w1 * a.y;
      acc[i * 4 + 2] += w1 * b.x;
      acc[i * 4 + 3] += w1 * b.y;
    }
    eA0 = eB0; eA1 = eB1; uA0 = uB0; uA1 = uB1;
    j = jn;
  }
  for (; j < deg; j += 4) {  // tail (and rare deg>64 overflow): 1 edge per quad, direct loads
    if (quad < deg - j) {
      unsigned s = (unsigned)src_sorted[off + j + quad];
      float w = fexp2(lrelu(es[s * 4u + hd] + myEd));
      sw += w;
      u32x4 u = *(const u32x4*)(h + (s << 8) + cOff);
#pragma unroll
      for (int i = 0; i < 4; i++) {
        f32x2 a = __builtin_amdgcn_cvt_pk_f32_fp8(u[i], false);
        f32x2 b = __builtin_amdgcn_cvt_pk_f32_fp8(u[i], true);
        acc[i * 4 + 0] += w * a.x;
        acc[i * 4 + 1] += w * a.y;
        acc[i * 4 + 2] += w * b.x;
        acc[i * 4 + 3] += w * b.y;
      }
    }
  }
  sw += __shfl_xor(sw, 16);
  sw += __shfl_xor(sw, 32);
#pragma unroll
  for (int k = 0; k < 16; k++) {
    acc[k] += __shfl_xor(acc[k], 16);
    acc[k] += __shfl_xor(acc[k], 32);
  }
  float invS = 1.0f / (sw + 1e-16f);
  if (quad == 0) {
    bf16x8 o0, o1;
#pragma unroll
    for (int k = 0; k < 16; k++) {
      int c = (int)hd * 64 + (k & 3) * 16 + (l16 & 3) * 4 + (k >> 2);  // cmap(l16*16+k)
      float v = fmaxf(acc[k] * invS + bias[c], 0.f);
      if (k < 8) o0[k] = (__bf16)v; else o1[k - 8] = (__bf16)v;
    }
    *(bf16x8*)&out[(size_t)node * 256 + l16 * 16] = o0;
    *(bf16x8*)&out[(size_t)node * 256 + l16 * 16 + 8] = o1;
  }
}

// ------- aggregation, HC=64 + FUSED final linear, register-index + pipelined gathers ------
__global__ void agg64_kernel(const unsigned char* __restrict__ h, const int* __restrict__ offsets,
                             const int* __restrict__ src_sorted, const float* __restrict__ es,
                             const float* __restrict__ ed, const float* __restrict__ bias,
                             const float* __restrict__ lin_w, float* __restrict__ pnode, int n) {
  int node = blockIdx.x * (blockDim.x >> 6) + (threadIdx.x >> 6);
  int lane = threadIdx.x & 63;
  if (node >= n) return;
  int grp = lane >> 3;
  int l8 = lane & 7;
  unsigned cOff = (unsigned)(l8 * 8);
  float myEd = ed[node];
  int off = offsets[node];
  int deg = offsets[node + 1] - off;
  int idxr = (lane < deg) ? src_sorted[off + lane] : 0;
  float acc[8] = {};
  float sw = 0.f;
  int npre = (deg < 64 ? deg : 64) & ~7;
  int j = 0;
  float eA = 0.f;
  u32x2 uA = {};
  if (j + 8 <= npre) {
    unsigned sA = (unsigned)__shfl(idxr, j + grp);
    eA = es[sA];
    uA = *(const u32x2*)(h + (sA << 6) + cOff);
  }
  while (j + 8 <= npre) {
    int jn = j + 8;
    float eB = 0.f;
    u32x2 uB = {};
    if (jn + 8 <= npre) {
      unsigned sB = (unsigned)__shfl(idxr, jn + grp);
      eB = es[sB];
      uB = *(const u32x2*)(h + (sB << 6) + cOff);
    }
    float w = fexp2(lrelu(eA + myEd));
    sw += w;
    {
      f32x2 a = __builtin_amdgcn_cvt_pk_f32_fp8(uA.x, false);
      f32x2 b = __builtin_amdgcn_cvt_pk_f32_fp8(uA.x, true);
      f32x2 c = __builtin_amdgcn_cvt_pk_f32_fp8(uA.y, false);
      f32x2 d = __builtin_amdgcn_cvt_pk_f32_fp8(uA.y, true);
      acc[0] += w * a.x; acc[1] += w * a.y; acc[2] += w * b.x; acc[3] += w * b.y;
      acc[4] += w * c.x; acc[5] += w * c.y; acc[6] += w * d.x; acc[7] += w * d.y;
    }
    eA = eB; uA = uB;
    j = jn;
  }
  for (; j < deg; j += 8) {  // tail (and rare deg>64 overflow)
    if (grp < deg - j) {
      unsigned s = (unsigned)src_sorted[off + j + grp];
      float w = fexp2(lrelu(es[s] + myEd));
      sw += w;
      u32x2 u = *(const u32x2*)(h + (s << 6) + cOff);
      f32x2 a = __builtin_amdgcn_cvt_pk_f32_fp8(u.x, false);
      f32x2 b = __builtin_amdgcn_cvt_pk_f32_fp8(u.x, true);
      f32x2 c = __builtin_amdgcn_cvt_pk_f32_fp8(u.y, false);
      f32x2 d = __builtin_amdgcn_cvt_pk_f32_fp8(u.y, true);
      acc[0] += w * a.x; acc[1] += w * a.y; acc[2] += w * b.x; acc[3] += w * b.y;
      acc[4] += w * c.x; acc[5] += w * c.y; acc[6] += w * d.x; acc[7] += w * d.y;
    }
  }
#pragma unroll
  for (int o = 8; o < 64; o <<= 1) {
    sw += __shfl_xor(sw, o);
#pragma unroll
    for (int k = 0; k < 8; k++) acc[k] += __shfl_xor(acc[k], o);
  }
  float invS = 1.0f / (sw + 1e-16f);
  float p = 0.f;
#pragma unroll
  for (int k = 0; k < 8; k++) {
    int c = (k & 3) * 16 + l8 * 2 + (k >> 2);  // cmap(l8*8+k)
    p += (acc[k] * invS + bias[c]) * lin_w[c];
  }
#pragma unroll
  for (int o = 1; o < 8; o <<= 1) p += __shfl_xor(p, o);
  if (lane == 0) pnode[node] = p;
}

// ---------------- FUSED pool+final: block g binary-searches its segment, reduces, writes out ----
static __device__ __forceinline__ int lowerb(const int* __restrict__ a, int n, int key) {
  int lo = 0, hi = n;
  while (lo < hi) {
    int mid = (lo + hi) >> 1;
    if (a[mid] < key) lo = mid + 1; else hi = mid;
  }
  return lo;
}

__global__ void poolfinal_kernel(const float* __restrict__ pnode, const int* __restrict__ batch,
                                 const float* __restrict__ lin_b, float* __restrict__ out, int n) {
  __shared__ float ws[4];
  int g = blockIdx.x;
  int start = lowerb(batch, n, g);
  int end = lowerb(batch, n, g + 1);
  float acc = 0.f;
  for (int i = start + threadIdx.x; i < end; i += 256) acc += pnode[i];
  for (int o = 32; o > 0; o >>= 1) acc += __shfl_down(acc, o);
  if ((threadIdx.x & 63) == 0) ws[threadIdx.x >> 6] = acc;
  __syncthreads();
  if (threadIdx.x == 0) {
    float total = ws[0] + ws[1] + ws[2] + ws[3];
    out[g] = total / fmaxf((float)(end - start), 1.0f) + lin_b[0];
  }
}

extern "C" void kernel_launch(void* const* d_in, const int* in_sizes, int n_in, void* d_out,
                              int out_size, void* d_ws, size_t ws_size, hipStream_t stream) {
  const float* x = (const float*)d_in[0];
  const int* edge_index = (const int*)d_in[1];
  const int* batch = (const int*)d_in[2];
  const float* W0 = (const float*)d_in[3];
  const float* a_src0 = (const float*)d_in[4];
  const float* a_dst0 = (const float*)d_in[5];
  const float* b0 = (const float*)d_in[6];
  const float* W1 = (const float*)d_in[7];
  const float* a_src1 = (const float*)d_in[8];
  const float* a_dst1 = (const float*)d_in[9];
  const float* b1 = (const float*)d_in[10];
  const float* W2 = (const float*)d_in[11];
  const float* a_src2 = (const float*)d_in[12];
  const float* a_dst2 = (const float*)d_in[13];
  const float* b2 = (const float*)d_in[14];
  const float* lin_w = (const float*)d_in[15];
  const float* lin_b = (const float*)d_in[16];
  float* out = (float*)d_out;

  const int N = in_sizes[2];      // 50000
  const int E = in_sizes[1] / 2;  // 800000
  const int EE = E + N;
  const int G = 64;
  const int FIN = in_sizes[0] / N;  // 128

  const int* srcArr = edge_index;
  const int* dstArr = edge_index + E;

  // workspace carve (256B aligned)
  size_t off = 0;
  auto alloc = [&](size_t bytes) -> void* {
    off = (off + 255) & ~(size_t)255;
    void* p = (char*)d_ws + off;
    off += bytes;
    return p;
  };
  unsigned char* hA = (unsigned char*)alloc((size_t)N * 256);  // GEMM out, fp8 permuted
  __bf16* hB = (__bf16*)alloc((size_t)N * 256 * 2);            // aggregate out, bf16 permuted
  unsigned char* h2 = (unsigned char*)alloc((size_t)N * 64);   // layer2 GEMM out, fp8 permuted
  float* pnode = (float*)alloc((size_t)N * 4);
  __bf16* Bt0 = (__bf16*)alloc((size_t)256 * FIN * 2);
  __bf16* Bt1 = (__bf16*)alloc((size_t)256 * 256 * 2);
  __bf16* Bt2 = (__bf16*)alloc((size_t)64 * 256 * 2);
  float* es = (float*)alloc((size_t)N * 4 * 4);
  float* ed = (float*)alloc((size_t)N * 4 * 4);
  int* offsets = (int*)alloc((size_t)(N + 1) * 4);
  int* src_sorted = (int*)alloc((size_t)EE * 4);
  int* bucket_cnt = (int*)alloc((size_t)4096 * 4);  // 196 buckets padded to 64B stride
  (void)ws_size;

  int NB = (N + 255) >> 8;  // dst-range buckets (256 nodes each)

  // part[] lives only between gemm_part and bucket_csr; hB is first written later by
  // agg256 -> alias part onto hB (NB*BCAP*4 = 6.4MB << 25.6MB).
  unsigned int* part = (unsigned int*)hB;

  int nwb = (N + 3) / 4;        // aggregate: one node per wave, 4 waves/block
  int gmx = (N + 63) / 64;      // GEMM M-blocks (64 rows each)
  int nA = (EE + 4095) / 4096;  // partition blocks (4096 edges each)

  // ---- prep (weight transposes, zero bucket counters) ----
  prep_kernel<<<576 + 16, 256, 0, stream>>>(W0, Bt0, W1, Bt1, W2, Bt2, FIN, bucket_cnt, 4096);

  // ---- layer-0 GEMM (reads f32 x directly, cvt in-register) + edge bucket-partition ----
  gemm_part_kernel<128, 4><<<gmx + nA, 256, 0, stream>>>(
      x, Bt0, a_src0, a_dst0, hA, es, ed, N, gmx, srcArr, dstArr, bucket_cnt, part, E, EE, N);

  // ---- per-bucket CSR finalize ----
  bucket_csr_kernel<<<NB, 1024, 0, stream>>>(part, bucket_cnt, offsets, src_sorted, N, EE);

  // ---- layer 0 aggregate ----
  agg256_kernel<<<nwb, 256, 0, stream>>>(hA, offsets, src_sorted, es, ed, b0, hB, N);

  // ---- layer 1: 256 -> 4x64 concat, relu ----
  gemm2_kernel<256, 4><<<gmx, 256, 0, stream>>>(hB, Bt1, a_src1, a_dst1, hA, es, ed, N);
  agg256_kernel<<<nwb, 256, 0, stream>>>(hA, offsets, src_sorted, es, ed, b1, hB, N);

  // ---- layer 2: 256 -> 1x64, single head; final linear fused into aggregate ----
  gemm2_kernel<256, 1><<<gmx, 256, 0, stream>>>(hB, Bt2, a_src2, a_dst2, h2, es, ed, N);
  agg64_kernel<<<nwb, 256, 0, stream>>>(h2, offsets, src_sorted, es, ed, b2, lin_w, pnode, N);

  // ---- fused global mean pool + bias (binary-search segments) ----
  poolfinal_kernel<<<G, 256, 0, stream>>>(pnode, batch, lin_b, out, N);
}